// Round 6
// baseline (1124.083 us; speedup 1.0000x reference)
//
#include <hip/hip_runtime.h>
#include <math.h>

#define BB 16
#define TT 12
#define NN 1024
#define FF 8
#define HH 64
#define EE 32768
#define DIN 320   // H * (2K+1)
#define ODIM 96   // F * HORIZON
#define APAD 40   // k_msq LDS row stride

typedef _Float16 v8h __attribute__((ext_vector_type(8)));
typedef float v4f __attribute__((ext_vector_type(4)));

__device__ __forceinline__ unsigned short f2h(float v) {
    _Float16 h = (_Float16)v;          // RNE v_cvt_f16_f32
    unsigned short u;
    __builtin_memcpy(&u, &h, 2);
    return u;
}
__device__ __forceinline__ float h2f(unsigned short u) {
    _Float16 h;
    __builtin_memcpy(&h, &u, 2);
    return (float)h;
}
// async global->LDS, 16B per lane; LDS dst = wave-uniform base + lane*16
__device__ __forceinline__ void gl_lds16(const void* g, void* l) {
    __builtin_amdgcn_global_load_lds(
        (const __attribute__((address_space(1))) unsigned int*)g,
        (__attribute__((address_space(3))) unsigned int*)l, 16, 0, 0);
}

// ---------------- edge_index insurance ----------------
__global__ void k_ei_detect(const int* __restrict__ ei_raw, int* __restrict__ flag) {
    __shared__ int s[256];
    s[threadIdx.x] = ei_raw[2 * threadIdx.x + 1];
    __syncthreads();
    for (int st = 128; st > 0; st >>= 1) {
        if (threadIdx.x < st) s[threadIdx.x] |= s[threadIdx.x + st];
        __syncthreads();
    }
    if (threadIdx.x == 0) flag[0] = (s[0] == 0) ? 1 : 0;
}
__global__ void k_ei_norm(const int* __restrict__ ei_raw, const int* __restrict__ flag,
                          int* __restrict__ ei32) {
    int j = blockIdx.x * 256 + threadIdx.x;
    ei32[j] = flag[0] ? ei_raw[2 * j] : ei_raw[j];
}

// ---------------- support normalization ----------------
__global__ void k_rowsum(const float* __restrict__ adj, float* __restrict__ rinv) {
    __shared__ float s[256];
    int i = blockIdx.x;
    float acc = 0.f;
    for (int j = threadIdx.x; j < NN; j += 256) acc += adj[i * NN + j];
    s[threadIdx.x] = acc;
    __syncthreads();
    for (int st = 128; st > 0; st >>= 1) {
        if (threadIdx.x < st) s[threadIdx.x] += s[threadIdx.x + st];
        __syncthreads();
    }
    if (threadIdx.x == 0) rinv[i] = (s[0] != 0.f) ? 1.f / s[0] : 0.f;
}
__global__ void k_colsum(const float* __restrict__ adj, float* __restrict__ cinv) {
    int j = blockIdx.x * 256 + threadIdx.x;
    float acc = 0.f;
    for (int i = 0; i < NN; i++) acc += adj[i * NN + j];
    cinv[j] = (acc != 0.f) ? 1.f / acc : 0.f;
}

// ---------------- Af -> plain rows 0..1023, Ab -> plain rows 2048..3071 (single fp16) ----------------
__global__ __launch_bounds__(256) void k_prepA(
        const float* __restrict__ adj, const float* __restrict__ rinv,
        const float* __restrict__ cinv, unsigned short* __restrict__ Mp) {
    int w0 = blockIdx.x * 64, v0 = blockIdx.y * 64;
    __shared__ float T[64][68];
    int row = threadIdx.x >> 2, cs = (threadIdx.x & 3) * 16;
    #pragma unroll
    for (int j = 0; j < 4; j++)
        *(float4*)&T[row][cs + j * 4] = *(const float4*)(adj + (size_t)(w0 + row) * NN + v0 + cs + j * 4);
    __syncthreads();
    {
        float sc = rinv[w0 + row];
        unsigned short h8[16];
        #pragma unroll
        for (int j = 0; j < 16; j++) h8[j] = f2h(T[row][cs + j] * sc);
        size_t ofs = (size_t)(w0 + row) * NN + v0 + cs;
        ((uint4*)(Mp + ofs))[0] = *(uint4*)&h8[0];
        ((uint4*)(Mp + ofs))[1] = *(uint4*)&h8[8];
    }
    {
        float sc = cinv[v0 + row];
        unsigned short h8[16];
        #pragma unroll
        for (int j = 0; j < 16; j++) h8[j] = f2h(T[cs + j][row] * sc);
        size_t ofs = (size_t)2048 * NN + (size_t)(v0 + row) * NN + w0 + cs;
        ((uint4*)(Mp + ofs))[0] = *(uint4*)&h8[0];
        ((uint4*)(Mp + ofs))[1] = *(uint4*)&h8[8];
    }
}

// ---------------- plain M rows (zz) squared: rows zz*2048 -> zz*2048+1024 ----------------
__global__ __launch_bounds__(256) void k_msq(unsigned short* __restrict__ M) {
    int zz = blockIdx.z;
    size_t srcb = (size_t)zz * 2048 * NN;
    size_t dstb = srcb + (size_t)1024 * NN;
    int w0 = blockIdx.x * 64, n0 = blockIdx.y * 64;

    __shared__ unsigned short sA[64 * APAD];
    __shared__ unsigned short sB[64 * APAD];

    int tid = threadIdx.x;
    int lane = tid & 63, wave = tid >> 6;
    int wr = (wave >> 1) * 32, wc = (wave & 1) * 32;
    int l15 = lane & 15, quad = lane >> 4;
    int arow = tid >> 2, akk = (tid & 3) * 8;
    int bkr = tid & 31, bc8 = (tid >> 5) * 8;

    v4f acc[2][2];
    #pragma unroll
    for (int i = 0; i < 2; i++)
        #pragma unroll
        for (int j = 0; j < 2; j++) { acc[i][j][0]=0.f; acc[i][j][1]=0.f; acc[i][j][2]=0.f; acc[i][j][3]=0.f; }

    for (int k0 = 0; k0 < NN; k0 += 32) {
        *(uint4*)&sA[arow * APAD + akk] = *(const uint4*)(M + srcb + (size_t)(w0 + arow) * NN + k0 + akk);
        uint4 bh = *(const uint4*)(M + srcb + (size_t)(k0 + bkr) * NN + n0 + bc8);
        const unsigned short* ph = (const unsigned short*)&bh;
        #pragma unroll
        for (int j = 0; j < 8; j++) sB[(bc8 + j) * APAD + bkr] = ph[j];
        __syncthreads();

        v8h a0 = *(const v8h*)&sA[(wr + l15) * APAD + quad * 8];
        v8h a1 = *(const v8h*)&sA[(wr + 16 + l15) * APAD + quad * 8];
        #pragma unroll
        for (int j = 0; j < 2; j++) {
            v8h bb = *(const v8h*)&sB[(wc + j * 16 + l15) * APAD + quad * 8];
            acc[0][j] = __builtin_amdgcn_mfma_f32_16x16x32_f16(a0, bb, acc[0][j], 0, 0, 0);
            acc[1][j] = __builtin_amdgcn_mfma_f32_16x16x32_f16(a1, bb, acc[1][j], 0, 0, 0);
        }
        __syncthreads();
    }

    #pragma unroll
    for (int i = 0; i < 2; i++)
        #pragma unroll
        for (int j = 0; j < 2; j++) {
            int rb = w0 + wr + i * 16 + quad * 4;
            int cc = n0 + wc + j * 16 + l15;
            #pragma unroll
            for (int rr = 0; rr < 4; rr++)
                M[dstb + (size_t)(rb + rr) * NN + cc] = f2h(acc[i][j][rr]);
        }
}

// ---------------- plain -> fragment-major: chunk t = (T*128 + kc)*64 + rowloc ----------------
__global__ void k_m2frag(const unsigned short* __restrict__ P, unsigned short* __restrict__ F) {
    size_t t = (size_t)blockIdx.x * 256 + threadIdx.x;
    int rowloc = (int)(t & 63);
    int kc = (int)((t >> 6) & 127);
    int T = (int)(t >> 13);
    size_t src = ((size_t)(T * 64 + rowloc) * NN) + kc * 8;
    *(uint4*)(F + t * 8) = *(const uint4*)(P + src);
}

// ---------------- x -> XallT rows: XallT[(t*16+b)*8+f][n] fp16 ----------------
__global__ void k_xT(const float* __restrict__ x, unsigned short* __restrict__ XallT) {
    int bx = blockIdx.x;            // t*16+b
    int t = bx >> 4, b = bx & 15;
    int tid = threadIdx.x;
    int f = tid & 7, half = tid >> 3;   // half 0..31
    const float* xs = x + ((size_t)b * TT + t) * NN * FF + f;
    int n0 = half * 32;
    unsigned short v[32];
    #pragma unroll
    for (int i = 0; i < 32; i++) v[i] = f2h(xs[(size_t)(n0 + i) * FF]);
    unsigned short* dst = XallT + ((size_t)bx * 8 + f) * NN + n0;
    #pragma unroll
    for (int i = 0; i < 4; i++) *(uint4*)(dst + i * 8) = *(uint4*)&v[i * 8];
}
// ---------------- emb -> XallT rows 1536..1599: embT[c][n] ----------------
__global__ void k_embT(const float* __restrict__ emb, unsigned short* __restrict__ XallT) {
    int c = blockIdx.x;
    int n0 = threadIdx.x * 4;
    unsigned short v[4];
    #pragma unroll
    for (int j = 0; j < 4; j++) v[j] = f2h(emb[(size_t)(n0 + j) * HH + c]);
    *(uint2*)(XallT + (size_t)(1536 + c) * NN + n0) = *(uint2*)v;
}

// ---------------- batched x-hop: 128x128 tile, 8 waves, 3-buf single-barrier pipeline ------------
__global__ __launch_bounds__(512) void k_hopX(
        const unsigned short* __restrict__ Mf,
        const unsigned short* __restrict__ XallT,
        unsigned short* __restrict__ AX, unsigned short* __restrict__ Eg) {
    int rt = blockIdx.x;
    int g = rt >> 3;
    int n0 = (rt & 7) * 128;
    int c0 = blockIdx.y * 128;

    __shared__ unsigned short sA[3][16 * 512];
    __shared__ unsigned short sX[3][16 * 512];

    int tid = threadIdx.x;
    int lane = tid & 63, wave = tid >> 6;   // 8 waves
    int rh = wave >> 2, cq = wave & 3;      // 2 row-halves x 4 col-quarters
    int l15 = lane & 15, quad = lane >> 4;

    v4f acc[4][2];
    #pragma unroll
    for (int i = 0; i < 4; i++)
        #pragma unroll
        for (int j = 0; j < 2; j++) { acc[i][j][0]=0.f; acc[i][j][1]=0.f; acc[i][j][2]=0.f; acc[i][j][3]=0.f; }

    auto STAGE = [&](int buf, int k0) {
        #pragma unroll
        for (int s = 0; s < 4; s++) {
            int id = wave + s * 8;
            if (id < 16) {
                int ah = id >> 3, kh = (id >> 2) & 1, rf = id & 3;
                const unsigned short* src = Mf +
                    ((size_t)(rt * 2 + ah) * 8192 +
                     (size_t)((k0 >> 3) + kh * 4 + quad) * 64 + rf * 16 + l15) * 8;
                gl_lds16(src, &sA[buf][id * 512]);
            } else {
                int xi = id - 16, cj = xi >> 1, kh = xi & 1;
                const unsigned short* src = XallT +
                    (size_t)(c0 + cj * 16 + l15) * NN + k0 + kh * 32 + quad * 8;
                gl_lds16(src, &sX[buf][xi * 512]);
            }
        }
    };

    STAGE(0, 0);
    STAGE(1, 64);

    int lu = lane * 8;
    for (int kt = 0; kt < 16; kt++) {
        int cur = kt % 3;
        if (kt < 15) asm volatile("s_waitcnt vmcnt(4)" ::: "memory");
        else         asm volatile("s_waitcnt vmcnt(0)" ::: "memory");
        __builtin_amdgcn_s_barrier();
        asm volatile("" ::: "memory");
        if (kt < 14) STAGE((kt + 2) % 3, (kt + 2) * 64);
        #pragma unroll
        for (int kh = 0; kh < 2; kh++) {
            v8h a[4], bx[2];
            #pragma unroll
            for (int rf = 0; rf < 4; rf++)
                a[rf] = *(const v8h*)&sA[cur][(rh * 8 + kh * 4 + rf) * 512 + lu];
            #pragma unroll
            for (int j = 0; j < 2; j++)
                bx[j] = *(const v8h*)&sX[cur][((cq * 2 + j) * 2 + kh) * 512 + lu];
            #pragma unroll
            for (int rf = 0; rf < 4; rf++)
                #pragma unroll
                for (int j = 0; j < 2; j++)
                    acc[rf][j] = __builtin_amdgcn_mfma_f32_16x16x32_f16(a[rf], bx[j], acc[rf][j], 0, 0, 0);
        }
        asm volatile("" ::: "memory");
    }

    #pragma unroll
    for (int rf = 0; rf < 4; rf++)
        #pragma unroll
        for (int j = 0; j < 2; j++) {
            int col = c0 + cq * 32 + j * 16 + l15;
            #pragma unroll
            for (int rr = 0; rr < 4; rr++) {
                int nrow = n0 + rh * 64 + rf * 16 + quad * 4 + rr;
                if (col < 1536) {
                    int tb = col >> 3, f = col & 7;
                    AX[((size_t)tb * NN + nrow) * 32 + g * 8 + f] = f2h(acc[rf][j][rr]);
                } else if (col < 1600) {
                    int cc = col - 1536;
                    Eg[((size_t)(g << 10) + nrow) * 64 + cc] = f2h(acc[rf][j][rr]);
                }
            }
        }
}

// ---------------- Veg[G][g*8+f][c] = W_enc @ W_G(x-block g) ----------------
__global__ void k_veg(const float* __restrict__ W_enc,
                      const float* __restrict__ W_r, const float* __restrict__ W_u,
                      const float* __restrict__ W_c, float* __restrict__ Veg) {
    int idx = blockIdx.x * 256 + threadIdx.x;    // 3*32*64
    int c = idx & 63;
    int gf = (idx >> 6) & 31;
    int G = idx >> 11;
    int g = gf >> 3, f = gf & 7;
    const float* W = (G == 0) ? W_r : ((G == 1) ? W_u : W_c);
    float acc = 0.f;
    for (int c2 = 0; c2 < 64; c2++)
        acc += W_enc[f * HH + c2] * W[(size_t)(g * 128 + c2) * HH + c];
    Veg[idx] = acc;
}

// ---------------- constE[G][n][c] = sum_g (Eg[g][n] + b_enc) @ W_G(x-block g) ----------------
__global__ void k_constE(const unsigned short* __restrict__ Eg, const float* __restrict__ b_enc,
                         const float* __restrict__ W_r, const float* __restrict__ W_u,
                         const float* __restrict__ W_c, float* __restrict__ constE) {
    int G = blockIdx.y;
    int n = blockIdx.x * 4 + (threadIdx.x >> 6);
    int c = threadIdx.x & 63;
    const float* W = (G == 0) ? W_r : ((G == 1) ? W_u : W_c);
    float acc = 0.f;
    for (int g = 0; g < 4; g++)
        for (int c2 = 0; c2 < 64; c2++)
            acc += (h2f(Eg[((size_t)(g << 10) + n) * 64 + c2]) + b_enc[c2]) *
                   W[(size_t)(g * 128 + c2) * HH + c];
    constE[((size_t)G << 16) + (size_t)n * 64 + c] = acc;
}

// ---------------- gate W -> fragment-major: k<32 from Veg, k>=32 from W h-block ----------------
__global__ void k_wfrag2(const float* __restrict__ W, const float* __restrict__ Veg,
                         unsigned short* __restrict__ Wf) {
    int idx = blockIdx.x * 256 + threadIdx.x;   // 4*9*512 = 18432
    int e = idx & 7, l = (idx >> 3) & 63;
    int rest = idx >> 9;
    int ks = rest % 9, cj = rest / 9;
    int c = cj * 16 + (l & 15);
    int k = ks * 32 + (l >> 4) * 8 + e;
    float w;
    if (k < 32) w = Veg[(size_t)k * 64 + c];
    else { int kk = k - 32; int g = kk >> 6, c2 = kk & 63; w = W[(size_t)(g * 128 + 64 + c2) * HH + c]; }
    Wf[idx] = f2h(w);
}
// ---------------- fused output W: Wf_o frag of (W_diff @ W_dec), 6 cj x 10 ks ----------------
__global__ void k_wfragO(const float* __restrict__ W_diff, const float* __restrict__ W_dec,
                         unsigned short* __restrict__ Wf) {
    int idx = blockIdx.x * 256 + threadIdx.x;   // 6*10*512 = 30720
    int e = idx & 7, l = (idx >> 3) & 63;
    int rest = idx >> 9;
    int ks = rest % 10, cj = rest / 10;
    int o = cj * 16 + (l & 15);
    int k = ks * 32 + (l >> 4) * 8 + e;
    float acc = 0.f;
    for (int c = 0; c < 64; c++) acc += W_diff[(size_t)k * HH + c] * W_dec[(size_t)c * ODIM + o];
    Wf[idx] = f2h(acc);
}
__global__ void k_bzd(const float* __restrict__ b_diff, const float* __restrict__ W_dec,
                      const float* __restrict__ b_dec, float* __restrict__ bzd) {
    int o = threadIdx.x;  // 96
    float acc = b_dec[o];
    for (int c = 0; c < 64; c++) acc += b_diff[c] * W_dec[(size_t)c * ODIM + o];
    bzd[o] = acc;
}

// ---------------- h-hop: 128x128 (b-pair) tile, 8 waves, 3-buf single-barrier pipeline ----------
__global__ __launch_bounds__(512) void k_hopA(
        const unsigned short* __restrict__ Mf,
        const unsigned short* __restrict__ Xb,
        unsigned short* __restrict__ Yout, int out_stride, int out_gmul, int out_off) {
    int rt = blockIdx.x;
    int g = rt >> 3;
    int n0 = (rt & 7) * 128;
    int bp = blockIdx.z;   // batch pair

    __shared__ unsigned short sA[3][16 * 512];
    __shared__ unsigned short sX[3][16 * 512];

    int tid = threadIdx.x;
    int lane = tid & 63, wave = tid >> 6;
    int rh = wave >> 2, cq = wave & 3;
    int l15 = lane & 15, quad = lane >> 4;

    const unsigned short* Xbase = Xb + (size_t)(bp * 2) * 64 * NN;  // 128 contiguous c-rows

    v4f acc[4][2];
    #pragma unroll
    for (int i = 0; i < 4; i++)
        #pragma unroll
        for (int j = 0; j < 2; j++) { acc[i][j][0]=0.f; acc[i][j][1]=0.f; acc[i][j][2]=0.f; acc[i][j][3]=0.f; }

    auto STAGE = [&](int buf, int k0) {
        #pragma unroll
        for (int s = 0; s < 4; s++) {
            int id = wave + s * 8;
            if (id < 16) {
                int ah = id >> 3, kh = (id >> 2) & 1, rf = id & 3;
                const unsigned short* src = Mf +
                    ((size_t)(rt * 2 + ah) * 8192 +
                     (size_t)((k0 >> 3) + kh * 4 + quad) * 64 + rf * 16 + l15) * 8;
                gl_lds16(src, &sA[buf][id * 512]);
            } else {
                int xi = id - 16, cj = xi >> 1, kh = xi & 1;
                const unsigned short* src = Xbase +
                    (size_t)(cj * 16 + l15) * NN + k0 + kh * 32 + quad * 8;
                gl_lds16(src, &sX[buf][xi * 512]);
            }
        }
    };

    STAGE(0, 0);
    STAGE(1, 64);

    int lu = lane * 8;
    for (int kt = 0; kt < 16; kt++) {
        int cur = kt % 3;
        if (kt < 15) asm volatile("s_waitcnt vmcnt(4)" ::: "memory");
        else         asm volatile("s_waitcnt vmcnt(0)" ::: "memory");
        __builtin_amdgcn_s_barrier();
        asm volatile("" ::: "memory");
        if (kt < 14) STAGE((kt + 2) % 3, (kt + 2) * 64);
        #pragma unroll
        for (int kh = 0; kh < 2; kh++) {
            v8h a[4], bx[2];
            #pragma unroll
            for (int rf = 0; rf < 4; rf++)
                a[rf] = *(const v8h*)&sA[cur][(rh * 8 + kh * 4 + rf) * 512 + lu];
            #pragma unroll
            for (int j = 0; j < 2; j++)
                bx[j] = *(const v8h*)&sX[cur][((cq * 2 + j) * 2 + kh) * 512 + lu];
            #pragma unroll
            for (int rf = 0; rf < 4; rf++)
                #pragma unroll
                for (int j = 0; j < 2; j++)
                    acc[rf][j] = __builtin_amdgcn_mfma_f32_16x16x32_f16(a[rf], bx[j], acc[rf][j], 0, 0, 0);
        }
        asm volatile("" ::: "memory");
    }

    #pragma unroll
    for (int rf = 0; rf < 4; rf++)
        #pragma unroll
        for (int j = 0; j < 2; j++) {
            int colloc = cq * 32 + j * 16 + l15;       // 0..127
            int b = bp * 2 + (colloc >> 6);
            int c = colloc & 63;
            unsigned short* Y = Yout + (size_t)b * NN * out_stride + out_gmul * g + out_off + c;
            int rbase = n0 + rh * 64 + rf * 16 + quad * 4;
            #pragma unroll
            for (int rr = 0; rr < 4; rr++)
                Y[(size_t)(rbase + rr) * out_stride] = f2h(acc[rf][j][rr]);
        }
}

// ---------------- gates via MFMA: K=288 = [AX(32) | Fh(256)]; rh -> Xh, u -> ubuf ----------------
__global__ __launch_bounds__(256) void k_gatesM(
        const unsigned short* __restrict__ AXt,   // [16][1024][32] (this t)
        const unsigned short* __restrict__ Fh,    // [16384][256]
        const unsigned short* __restrict__ Wf_r, const unsigned short* __restrict__ Wf_u,
        const float* __restrict__ b_r, const float* __restrict__ b_u,
        const float* __restrict__ constE,         // [3][1024][64]
        const float* __restrict__ h,
        unsigned short* __restrict__ Xh, float* __restrict__ ubuf) {
    int row0 = blockIdx.x * 64;
    int b = row0 >> 10, n0g = row0 & 1023;
    int tid = threadIdx.x, lane = tid & 63, wave = tid >> 6;
    int gate = wave >> 1;              // 0 = r, 1 = u
    int rhalf = (wave & 1) * 32;
    int l15 = lane & 15, quad = lane >> 4;
    const unsigned short* Wf = gate ? Wf_u : Wf_r;
    const float* bias = gate ? b_u : b_r;
    const float* cE = constE + ((size_t)gate << 16);

    __shared__ unsigned short sT[64 * 72];

    v4f acc[2][4];
    #pragma unroll
    for (int rf = 0; rf < 2; rf++)
        #pragma unroll
        for (int cj = 0; cj < 4; cj++) { acc[rf][cj][0]=0.f; acc[rf][cj][1]=0.f; acc[rf][cj][2]=0.f; acc[rf][cj][3]=0.f; }

    const unsigned short* ax = AXt + ((size_t)b * NN + n0g + rhalf + l15) * 32 + quad * 8;
    const unsigned short* fh = Fh + (size_t)(row0 + rhalf + l15) * 256 + quad * 8;
    {
        v8h a0 = *(const v8h*)ax;
        v8h a1 = *(const v8h*)(ax + 16 * 32);
        #pragma unroll
        for (int cj = 0; cj < 4; cj++) {
            v8h bf = *(const v8h*)(Wf + (size_t)(cj * 9) * 512 + lane * 8);
            acc[0][cj] = __builtin_amdgcn_mfma_f32_16x16x32_f16(a0, bf, acc[0][cj], 0, 0, 0);
            acc[1][cj] = __builtin_amdgcn_mfma_f32_16x16x32_f16(a1, bf, acc[1][cj], 0, 0, 0);
        }
    }
    #pragma unroll
    for (int ks = 1; ks < 9; ks++) {
        v8h a0 = *(const v8h*)(fh + (ks - 1) * 32);
        v8h a1 = *(const v8h*)(fh + 16 * 256 + (ks - 1) * 32);
        #pragma unroll
        for (int cj = 0; cj < 4; cj++) {
            v8h bf = *(const v8h*)(Wf + (size_t)(cj * 9 + ks) * 512 + lane * 8);
            acc[0][cj] = __builtin_amdgcn_mfma_f32_16x16x32_f16(a0, bf, acc[0][cj], 0, 0, 0);
            acc[1][cj] = __builtin_amdgcn_mfma_f32_16x16x32_f16(a1, bf, acc[1][cj], 0, 0, 0);
        }
    }

    if (gate == 0) {
        #pragma unroll
        for (int rf = 0; rf < 2; rf++)
            #pragma unroll
            for (int cj = 0; cj < 4; cj++) {
                int c = cj * 16 + l15;
                float bb = bias[c];
                #pragma unroll
                for (int rr = 0; rr < 4; rr++) {
                    int nloc = rhalf + rf * 16 + quad * 4 + rr;
                    float pre = acc[rf][cj][rr] + bb + cE[(size_t)(n0g + nloc) * 64 + c];
                    float r = 1.f / (1.f + expf(-pre));
                    sT[c * 72 + nloc] = f2h(r * h[(size_t)(row0 + nloc) * HH + c]);
                }
            }
    } else {
        #pragma unroll
        for (int rf = 0; rf < 2; rf++)
            #pragma unroll
            for (int cj = 0; cj < 4; cj++) {
                int c = cj * 16 + l15;
                float bb = bias[c];
                #pragma unroll
                for (int rr = 0; rr < 4; rr++) {
                    int nloc = rhalf + rf * 16 + quad * 4 + rr;
                    float pre = acc[rf][cj][rr] + bb + cE[(size_t)(n0g + nloc) * 64 + c];
                    float u = 1.f / (1.f + expf(-pre));
                    ubuf[(size_t)(row0 + nloc) * HH + c] = u;
                }
            }
    }
    __syncthreads();
    #pragma unroll
    for (int i = 0; i < 2; i++) {
        int ii = tid * 2 + i;
        int c = ii >> 3, n8 = (ii & 7) * 8;
        *(uint4*)(Xh + ((size_t)b * 64 + c) * NN + n0g + n8) = *(uint4*)&sT[c * 72 + n8];
    }
}

// ---------------- candidate via MFMA (K=288) + h update; new h -> h f32 AND Xh fp16 --------------
__global__ __launch_bounds__(256) void k_candM(
        const unsigned short* __restrict__ AXt,
        const unsigned short* __restrict__ Fh,
        const unsigned short* __restrict__ Wf_c, const float* __restrict__ b_c,
        const float* __restrict__ constE,
        const float* __restrict__ ubuf,
        float* __restrict__ h, unsigned short* __restrict__ Xh) {
    int row0 = blockIdx.x * 64;
    int b = row0 >> 10, n0g = row0 & 1023;
    int tid = threadIdx.x, lane = tid & 63, wave = tid >> 6;
    int l15 = lane & 15, quad = lane >> 4;
    const float* cE = constE + ((size_t)2 << 16);

    __shared__ unsigned short sT[64 * 72];

    v4f acc[4];
    #pragma unroll
    for (int cj = 0; cj < 4; cj++) { acc[cj][0]=0.f; acc[cj][1]=0.f; acc[cj][2]=0.f; acc[cj][3]=0.f; }

    const unsigned short* ax = AXt + ((size_t)b * NN + n0g + wave * 16 + l15) * 32 + quad * 8;
    const unsigned short* fh = Fh + (size_t)(row0 + wave * 16 + l15) * 256 + quad * 8;
    {
        v8h a = *(const v8h*)ax;
        #pragma unroll
        for (int cj = 0; cj < 4; cj++) {
            v8h bf = *(const v8h*)(Wf_c + (size_t)(cj * 9) * 512 + lane * 8);
            acc[cj] = __builtin_amdgcn_mfma_f32_16x16x32_f16(a, bf, acc[cj], 0, 0, 0);
        }
    }
    #pragma unroll
    for (int ks = 1; ks < 9; ks++) {
        v8h a = *(const v8h*)(fh + (ks - 1) * 32);
        #pragma unroll
        for (int cj = 0; cj < 4; cj++) {
            v8h bf = *(const v8h*)(Wf_c + (size_t)(cj * 9 + ks) * 512 + lane * 8);
            acc[cj] = __builtin_amdgcn_mfma_f32_16x16x32_f16(a, bf, acc[cj], 0, 0, 0);
        }
    }

    #pragma unroll
    for (int cj = 0; cj < 4; cj++) {
        int c = cj * 16 + l15;
        float bb = b_c[c];
        #pragma unroll
        for (int rr = 0; rr < 4; rr++) {
            int nloc = wave * 16 + quad * 4 + rr;
            size_t o = (size_t)(row0 + nloc) * HH + c;
            float pre = acc[cj][rr] + bb + cE[(size_t)(n0g + nloc) * 64 + c];
            float cv = tanhf(pre);
            float u = ubuf[o];
            float hv = h[o];
            float hn = u * hv + (1.f - u) * cv;
            h[o] = hn;
            sT[c * 72 + nloc] = f2h(hn);
        }
    }
    __syncthreads();
    #pragma unroll
    for (int i = 0; i < 2; i++) {
        int ii = tid * 2 + i;
        int c = ii >> 3, n8 = (ii & 7) * 8;
        *(uint4*)(Xh + ((size_t)b * 64 + c) * NN + n0g + n8) = *(uint4*)&sT[c * 72 + n8];
    }
}

// ---------------- out = featd @ (W_diff@W_dec) + bzd, scattered to [b][t][n][f] ----------------
__global__ __launch_bounds__(256) void k_out(
        const unsigned short* __restrict__ featd,
        const unsigned short* __restrict__ Wf_o, const float* __restrict__ bzd,
        float* __restrict__ out) {
    int row0 = blockIdx.x * 64;
    int tid = threadIdx.x, lane = tid & 63, wave = tid >> 6;
    int l15 = lane & 15, quad = lane >> 4;

    v4f acc[6];
    #pragma unroll
    for (int cj = 0; cj < 6; cj++) { acc[cj][0]=0.f; acc[cj][1]=0.f; acc[cj][2]=0.f; acc[cj][3]=0.f; }

    const unsigned short* fbase = featd + (size_t)(row0 + wave * 16 + l15) * DIN + quad * 8;
    #pragma unroll 2
    for (int ks = 0; ks < 10; ks++) {
        v8h a = *(const v8h*)(fbase + ks * 32);
        #pragma unroll
        for (int cj = 0; cj < 6; cj++) {
            v8h bf = *(const v8h*)(Wf_o + (size_t)(cj * 10 + ks) * 512 + lane * 8);
            acc[cj] = __builtin_amdgcn_mfma_f32_16x16x32_f16(a, bf, acc[cj], 0, 0, 0);
        }
    }
    #pragma unroll
    for (int cj = 0; cj < 6; cj++) {
        int o = cj * 16 + l15;
        int t = o >> 3, f = o & 7;
        float bb = bzd[o];
        #pragma unroll
        for (int rr = 0; rr < 4; rr++) {
            int row = row0 + wave * 16 + quad * 4 + rr;
            int b = row >> 10, n = row & 1023;
            out[(((size_t)b * TT + t) * NN + n) * FF + f] = acc[cj][rr] + bb;
        }
    }
}

// ---------------- DiffConv operator build ----------------
__global__ void k_deg(const int* __restrict__ ei32, const float* __restrict__ ew,
                      float* __restrict__ degd, float* __restrict__ degs) {
    int e = blockIdx.x * 256 + threadIdx.x;
    float w = ew[e];
    atomicAdd(&degd[ei32[EE + e]], w);
    atomicAdd(&degs[ei32[e]], w);
}
__global__ void k_spadd(const int* __restrict__ ei32, const float* __restrict__ ew,
                        const float* __restrict__ degd, const float* __restrict__ degs,
                        float* __restrict__ temp) {
    int e = blockIdx.x * 256 + threadIdx.x;
    int s = ei32[e], d = ei32[EE + e];
    float w = ew[e];
    float dd = degd[d], ds = degs[s];
    float wfv = dd > 0.f ? w / dd : 0.f;
    float wbv = ds > 0.f ? w / ds : 0.f;
    atomicAdd(&temp[(size_t)d * NN + s], wfv);
    atomicAdd(&temp[(size_t)NN * NN + (size_t)s * NN + d], wbv);
}
__global__ void k_spconv(const float* __restrict__ temp, unsigned short* __restrict__ Mp) {
    size_t i0 = ((size_t)blockIdx.x * 256 + threadIdx.x) * 8;
    size_t dst = (i0 < (size_t)NN * NN) ? i0 : i0 + (size_t)NN * NN;
    unsigned short h8[8];
    #pragma unroll
    for (int j = 0; j < 8; j++) h8[j] = f2h(temp[i0 + j]);
    *(uint4*)(Mp + dst) = *(uint4*)h8;
}

__global__ void k_featd_h(const float* __restrict__ h, unsigned short* __restrict__ featd) {
    size_t idx = (size_t)blockIdx.x * 256 + threadIdx.x;
    size_t row = idx >> 6; int c = (int)(idx & 63);
    featd[row * DIN + c] = f2h(h[idx]);
}

extern "C" void kernel_launch(void* const* d_in, const int* in_sizes, int n_in,
                              void* d_out, int out_size, void* d_ws, size_t ws_size,
                              hipStream_t stream) {
    const float* x      = (const float*)d_in[0];
    const int*   eiraw  = (const int*)  d_in[1];
    const float* ew     = (const float*)d_in[2];
    const float* adj    = (const float*)d_in[3];
    const float* W_enc  = (const float*)d_in[4];
    const float* b_enc  = (const float*)d_in[5];
    const float* emb    = (const float*)d_in[6];
    const float* W_r    = (const float*)d_in[7];
    const float* b_r    = (const float*)d_in[8];
    const float* W_u    = (const float*)d_in[9];
    const float* b_u    = (const float*)d_in[10];
    const float* W_c    = (const float*)d_in[11];
    const float* b_c    = (const float*)d_in[12];
    const float* W_diff = (const float*)d_in[13];
    const float* b_diff = (const float*)d_in[14];
    const float* W_dec  = (const float*)d_in[15];
    const float* b_dec  = (const float*)d_in[16];

    // ---- workspace ~53 MiB ----
    unsigned short* Mf    = (unsigned short*)d_ws;            // 8 MiB
    unsigned short* Xh    = Mf + (size_t)4096 * NN;           // 2 MiB
    unsigned short* FD    = Xh + (size_t)BB * 64 * NN;        // 10 MiB: featd [16384][320]; Fh overlay
    unsigned short* Fh    = FD;                               //   [16384][256]
    unsigned short* featd = FD;
    float* h    = (float*)(FD + (size_t)BB * NN * DIN);       // 4 MiB
    float* ubuf = h + (size_t)BB * NN * HH;                   // 4 MiB
    unsigned short* AXall = (unsigned short*)(ubuf + (size_t)BB * NN * HH); // 12 MiB [tb][n][32]
    unsigned short* Mp    = AXall;                            // 8 MiB overlay (prep & readout)
    unsigned short* XallT = AXall + (size_t)192 * NN * 32;    // 3.125 MiB [1600][1024]
    unsigned short* Eg    = XallT + (size_t)1600 * NN;        // 0.5 MiB [4][1024][64]
    float* sptmp  = (float*)(Eg + (size_t)4 * NN * 64);       // 8 MiB
    float* constE = sptmp + (size_t)2 * NN * NN;              // 768 KiB [3][1024][64]
    float* Veg    = constE + (size_t)3 * NN * 64;             // 24 KiB [3][32][64]
    unsigned short* Wf_r = (unsigned short*)(Veg + 3 * 32 * 64);
    unsigned short* Wf_u = Wf_r + 4 * 9 * 512;
    unsigned short* Wf_c = Wf_u + 4 * 9 * 512;
    unsigned short* Wf_o = Wf_c + 4 * 9 * 512;                // 6*10*512 = 30720
    float* bzd  = (float*)(Wf_o + 30720);
    float* rinv = bzd + ODIM;
    float* cinv = rinv + NN;
    int*   eifl = (int*)(cinv + NN);
    int*   ei32 = eifl + 4;
    float* degd = (float*)(ei32 + 2 * EE);
    float* degs = degd + NN;

    hipMemsetAsync(h, 0, (size_t)BB * NN * HH * 4, stream);
    hipMemsetAsync(Xh, 0, (size_t)BB * 64 * NN * 2, stream);   // h = 0 at t=0

    // ---- build plain M = [Af; Af^2; Ab; Ab^2] (fp16), convert to fragment-major ----
    k_rowsum<<<NN, 256, 0, stream>>>(adj, rinv);
    k_colsum<<<NN / 256, 256, 0, stream>>>(adj, cinv);
    k_prepA<<<dim3(16, 16), 256, 0, stream>>>(adj, rinv, cinv, Mp);
    k_msq<<<dim3(16, 16, 2), 256, 0, stream>>>(Mp);
    k_m2frag<<<2048, 256, 0, stream>>>(Mp, Mf);

    // ---- x/emb transposes, batched x-hop (overwrites Mp region), const folds ----
    k_xT<<<TT * BB, 256, 0, stream>>>(x, XallT);
    k_embT<<<64, 256, 0, stream>>>(emb, XallT);
    k_hopX<<<dim3(32, 13), 512, 0, stream>>>(Mf, XallT, AXall, Eg);
    k_veg<<<24, 256, 0, stream>>>(W_enc, W_r, W_u, W_c, Veg);
    k_constE<<<dim3(256, 3), 256, 0, stream>>>(Eg, b_enc, W_r, W_u, W_c, constE);
    k_wfrag2<<<72, 256, 0, stream>>>(W_r, Veg, Wf_r);
    k_wfrag2<<<72, 256, 0, stream>>>(W_u, Veg + 2048, Wf_u);
    k_wfrag2<<<72, 256, 0, stream>>>(W_c, Veg + 4096, Wf_c);
    k_wfragO<<<120, 256, 0, stream>>>(W_diff, W_dec, Wf_o);
    k_bzd<<<1, ODIM, 0, stream>>>(b_diff, W_dec, b_dec, bzd);

    for (int t = 0; t < TT; t++) {
        const unsigned short* AXt = AXall + (size_t)t * BB * NN * 32;
        // 4 operators @ h -> Fh [row][g*64+c]
        k_hopA<<<dim3(32, 1, 8), 512, 0, stream>>>(Mf, Xh, Fh, 256, 64, 0);
        // gates: rh -> Xh (fp16), u -> ubuf (f32)
        k_gatesM<<<BB * NN / 64, 256, 0, stream>>>(AXt, Fh, Wf_r, Wf_u, b_r, b_u, constE, h, Xh, ubuf);
        // 4 operators @ rh -> Fh
        k_hopA<<<dim3(32, 1, 8), 512, 0, stream>>>(Mf, Xh, Fh, 256, 64, 0);
        // candidate + h update
        k_candM<<<BB * NN / 64, 256, 0, stream>>>(AXt, Fh, Wf_c, b_c, constE, ubuf, h, Xh);
    }

    // ---- DiffConv readout ----
    k_ei_detect<<<1, 256, 0, stream>>>(eiraw, eifl);
    k_ei_norm<<<2 * EE / 256, 256, 0, stream>>>(eiraw, eifl, ei32);
    hipMemsetAsync(degd, 0, (size_t)2 * NN * 4, stream);
    hipMemsetAsync(sptmp, 0, (size_t)2 * NN * NN * 4, stream);
    k_deg<<<EE / 256, 256, 0, stream>>>(ei32, ew, degd, degs);
    k_spadd<<<EE / 256, 256, 0, stream>>>(ei32, ew, degd, degs, sptmp);
    k_spconv<<<2 * NN * NN / (256 * 8), 256, 0, stream>>>(sptmp, Mp);
    k_msq<<<dim3(16, 16, 2), 256, 0, stream>>>(Mp);
    k_m2frag<<<2048, 256, 0, stream>>>(Mp, Mf);
    k_featd_h<<<BB * NN * HH / 256, 256, 0, stream>>>(h, featd);
    // [Sf;Sf2;Sb;Sb2] @ h (fp16 in Xh) -> featd cols 64 + g*64
    k_hopA<<<dim3(32, 1, 8), 512, 0, stream>>>(Mf, Xh, featd, DIN, 64, 64);
    k_out<<<BB * NN / 64, 256, 0, stream>>>(featd, Wf_o, bzd, (float*)d_out);
}

// Round 7
// 998.839 us; speedup vs baseline: 1.1254x; 1.1254x over previous
//
#include <hip/hip_runtime.h>
#include <math.h>

#define BB 16
#define TT 12
#define NN 1024
#define FF 8
#define HH 64
#define EE 32768
#define DIN 320   // H * (2K+1)
#define ODIM 96   // F * HORIZON
#define APAD 40   // k_msq LDS row stride

typedef _Float16 v8h __attribute__((ext_vector_type(8)));
typedef float v4f __attribute__((ext_vector_type(4)));

__device__ __forceinline__ unsigned short f2h(float v) {
    _Float16 h = (_Float16)v;          // RNE v_cvt_f16_f32
    unsigned short u;
    __builtin_memcpy(&u, &h, 2);
    return u;
}
__device__ __forceinline__ float h2f(unsigned short u) {
    _Float16 h;
    __builtin_memcpy(&h, &u, 2);
    return (float)h;
}
// async global->LDS, 16B per lane; LDS dst = wave-uniform base + lane*16
__device__ __forceinline__ void gl_lds16(const void* g, void* l) {
    __builtin_amdgcn_global_load_lds(
        (const __attribute__((address_space(1))) unsigned int*)g,
        (__attribute__((address_space(3))) unsigned int*)l, 16, 0, 0);
}

// ---------------- edge_index insurance ----------------
__global__ void k_ei_detect(const int* __restrict__ ei_raw, int* __restrict__ flag) {
    __shared__ int s[256];
    s[threadIdx.x] = ei_raw[2 * threadIdx.x + 1];
    __syncthreads();
    for (int st = 128; st > 0; st >>= 1) {
        if (threadIdx.x < st) s[threadIdx.x] |= s[threadIdx.x + st];
        __syncthreads();
    }
    if (threadIdx.x == 0) flag[0] = (s[0] == 0) ? 1 : 0;
}
__global__ void k_ei_norm(const int* __restrict__ ei_raw, const int* __restrict__ flag,
                          int* __restrict__ ei32) {
    int j = blockIdx.x * 256 + threadIdx.x;
    ei32[j] = flag[0] ? ei_raw[2 * j] : ei_raw[j];
}

// ---------------- support normalization ----------------
__global__ void k_rowsum(const float* __restrict__ adj, float* __restrict__ rinv) {
    __shared__ float s[256];
    int i = blockIdx.x;
    float acc = 0.f;
    for (int j = threadIdx.x; j < NN; j += 256) acc += adj[i * NN + j];
    s[threadIdx.x] = acc;
    __syncthreads();
    for (int st = 128; st > 0; st >>= 1) {
        if (threadIdx.x < st) s[threadIdx.x] += s[threadIdx.x + st];
        __syncthreads();
    }
    if (threadIdx.x == 0) rinv[i] = (s[0] != 0.f) ? 1.f / s[0] : 0.f;
}
__global__ void k_colsum(const float* __restrict__ adj, float* __restrict__ cinv) {
    int j = blockIdx.x * 256 + threadIdx.x;
    float acc = 0.f;
    for (int i = 0; i < NN; i++) acc += adj[i * NN + j];
    cinv[j] = (acc != 0.f) ? 1.f / acc : 0.f;
}

// ---------------- Af -> plain rows 0..1023, Ab -> plain rows 2048..3071 (single fp16) ----------------
__global__ __launch_bounds__(256) void k_prepA(
        const float* __restrict__ adj, const float* __restrict__ rinv,
        const float* __restrict__ cinv, unsigned short* __restrict__ Mp) {
    int w0 = blockIdx.x * 64, v0 = blockIdx.y * 64;
    __shared__ float T[64][68];
    int row = threadIdx.x >> 2, cs = (threadIdx.x & 3) * 16;
    #pragma unroll
    for (int j = 0; j < 4; j++)
        *(float4*)&T[row][cs + j * 4] = *(const float4*)(adj + (size_t)(w0 + row) * NN + v0 + cs + j * 4);
    __syncthreads();
    {
        float sc = rinv[w0 + row];
        unsigned short h8[16];
        #pragma unroll
        for (int j = 0; j < 16; j++) h8[j] = f2h(T[row][cs + j] * sc);
        size_t ofs = (size_t)(w0 + row) * NN + v0 + cs;
        ((uint4*)(Mp + ofs))[0] = *(uint4*)&h8[0];
        ((uint4*)(Mp + ofs))[1] = *(uint4*)&h8[8];
    }
    {
        float sc = cinv[v0 + row];
        unsigned short h8[16];
        #pragma unroll
        for (int j = 0; j < 16; j++) h8[j] = f2h(T[cs + j][row] * sc);
        size_t ofs = (size_t)2048 * NN + (size_t)(v0 + row) * NN + w0 + cs;
        ((uint4*)(Mp + ofs))[0] = *(uint4*)&h8[0];
        ((uint4*)(Mp + ofs))[1] = *(uint4*)&h8[8];
    }
}

// ---------------- plain M rows (zz) squared: rows zz*2048 -> zz*2048+1024 ----------------
__global__ __launch_bounds__(256) void k_msq(unsigned short* __restrict__ M) {
    int zz = blockIdx.z;
    size_t srcb = (size_t)zz * 2048 * NN;
    size_t dstb = srcb + (size_t)1024 * NN;
    int w0 = blockIdx.x * 64, n0 = blockIdx.y * 64;

    __shared__ unsigned short sA[64 * APAD];
    __shared__ unsigned short sB[64 * APAD];

    int tid = threadIdx.x;
    int lane = tid & 63, wave = tid >> 6;
    int wr = (wave >> 1) * 32, wc = (wave & 1) * 32;
    int l15 = lane & 15, quad = lane >> 4;
    int arow = tid >> 2, akk = (tid & 3) * 8;
    int bkr = tid & 31, bc8 = (tid >> 5) * 8;

    v4f acc[2][2];
    #pragma unroll
    for (int i = 0; i < 2; i++)
        #pragma unroll
        for (int j = 0; j < 2; j++) { acc[i][j][0]=0.f; acc[i][j][1]=0.f; acc[i][j][2]=0.f; acc[i][j][3]=0.f; }

    for (int k0 = 0; k0 < NN; k0 += 32) {
        *(uint4*)&sA[arow * APAD + akk] = *(const uint4*)(M + srcb + (size_t)(w0 + arow) * NN + k0 + akk);
        uint4 bh = *(const uint4*)(M + srcb + (size_t)(k0 + bkr) * NN + n0 + bc8);
        const unsigned short* ph = (const unsigned short*)&bh;
        #pragma unroll
        for (int j = 0; j < 8; j++) sB[(bc8 + j) * APAD + bkr] = ph[j];
        __syncthreads();

        v8h a0 = *(const v8h*)&sA[(wr + l15) * APAD + quad * 8];
        v8h a1 = *(const v8h*)&sA[(wr + 16 + l15) * APAD + quad * 8];
        #pragma unroll
        for (int j = 0; j < 2; j++) {
            v8h bb = *(const v8h*)&sB[(wc + j * 16 + l15) * APAD + quad * 8];
            acc[0][j] = __builtin_amdgcn_mfma_f32_16x16x32_f16(a0, bb, acc[0][j], 0, 0, 0);
            acc[1][j] = __builtin_amdgcn_mfma_f32_16x16x32_f16(a1, bb, acc[1][j], 0, 0, 0);
        }
        __syncthreads();
    }

    #pragma unroll
    for (int i = 0; i < 2; i++)
        #pragma unroll
        for (int j = 0; j < 2; j++) {
            int rb = w0 + wr + i * 16 + quad * 4;
            int cc = n0 + wc + j * 16 + l15;
            #pragma unroll
            for (int rr = 0; rr < 4; rr++)
                M[dstb + (size_t)(rb + rr) * NN + cc] = f2h(acc[i][j][rr]);
        }
}

// ---------------- plain -> fragment-major: chunk t = (T*128 + kc)*64 + rowloc ----------------
__global__ void k_m2frag(const unsigned short* __restrict__ P, unsigned short* __restrict__ F) {
    size_t t = (size_t)blockIdx.x * 256 + threadIdx.x;
    int rowloc = (int)(t & 63);
    int kc = (int)((t >> 6) & 127);
    int T = (int)(t >> 13);
    size_t src = ((size_t)(T * 64 + rowloc) * NN) + kc * 8;
    *(uint4*)(F + t * 8) = *(const uint4*)(P + src);
}

// ---------------- x -> XallT rows: XallT[(t*16+b)*8+f][n] fp16 ----------------
__global__ void k_xT(const float* __restrict__ x, unsigned short* __restrict__ XallT) {
    int bx = blockIdx.x;            // t*16+b
    int t = bx >> 4, b = bx & 15;
    int tid = threadIdx.x;
    int f = tid & 7, half = tid >> 3;   // half 0..31
    const float* xs = x + ((size_t)b * TT + t) * NN * FF + f;
    int n0 = half * 32;
    unsigned short v[32];
    #pragma unroll
    for (int i = 0; i < 32; i++) v[i] = f2h(xs[(size_t)(n0 + i) * FF]);
    unsigned short* dst = XallT + ((size_t)bx * 8 + f) * NN + n0;
    #pragma unroll
    for (int i = 0; i < 4; i++) *(uint4*)(dst + i * 8) = *(uint4*)&v[i * 8];
}
// ---------------- emb -> XallT rows 1536..1599: embT[c][n] ----------------
__global__ void k_embT(const float* __restrict__ emb, unsigned short* __restrict__ XallT) {
    int c = blockIdx.x;
    int n0 = threadIdx.x * 4;
    unsigned short v[4];
    #pragma unroll
    for (int j = 0; j < 4; j++) v[j] = f2h(emb[(size_t)(n0 + j) * HH + c]);
    *(uint2*)(XallT + (size_t)(1536 + c) * NN + n0) = *(uint2*)v;
}

// ---------------- batched x-hop: 128x128 tile, XCD-grouped 1D grid (bid = y*32 + rt) ------------
__global__ __launch_bounds__(512) void k_hopX(
        const unsigned short* __restrict__ Mf,
        const unsigned short* __restrict__ XallT,
        unsigned short* __restrict__ AX, unsigned short* __restrict__ Eg) {
    int bid = blockIdx.x;
    int rt = bid & 31;          // XCD = bid%8 = rt%8 -> same-rt blocks share an XCD L2
    int y  = bid >> 5;
    int g = rt >> 3;
    int n0 = (rt & 7) * 128;
    int c0 = y * 128;

    __shared__ unsigned short sA[2][16 * 512];
    __shared__ unsigned short sX[2][16 * 512];

    int tid = threadIdx.x;
    int lane = tid & 63, wave = tid >> 6;   // 8 waves
    int rh = wave >> 2, cq = wave & 3;      // 2 row-halves x 4 col-quarters
    int l15 = lane & 15, quad = lane >> 4;

    v4f acc[4][2];
    #pragma unroll
    for (int i = 0; i < 4; i++)
        #pragma unroll
        for (int j = 0; j < 2; j++) { acc[i][j][0]=0.f; acc[i][j][1]=0.f; acc[i][j][2]=0.f; acc[i][j][3]=0.f; }

    auto STAGE = [&](int buf, int k0) {
        #pragma unroll
        for (int s = 0; s < 4; s++) {
            int id = wave + s * 8;
            if (id < 16) {
                int ah = id >> 3, kh = (id >> 2) & 1, rf = id & 3;
                const unsigned short* src = Mf +
                    ((size_t)(rt * 2 + ah) * 8192 +
                     (size_t)((k0 >> 3) + kh * 4 + quad) * 64 + rf * 16 + l15) * 8;
                gl_lds16(src, &sA[buf][id * 512]);
            } else {
                int xi = id - 16, cj = xi >> 1, kh = xi & 1;
                const unsigned short* src = XallT +
                    (size_t)(c0 + cj * 16 + l15) * NN + k0 + kh * 32 + quad * 8;
                gl_lds16(src, &sX[buf][xi * 512]);
            }
        }
    };

    STAGE(0, 0);
    STAGE(1, 64);

    int lu = lane * 8;
    for (int kt = 0; kt < 16; kt++) {
        int cur = kt & 1;
        if (kt < 15) asm volatile("s_waitcnt vmcnt(4)" ::: "memory");
        else         asm volatile("s_waitcnt vmcnt(0)" ::: "memory");
        __builtin_amdgcn_s_barrier();
        asm volatile("" ::: "memory");
        #pragma unroll
        for (int kh = 0; kh < 2; kh++) {
            v8h a[4], bx[2];
            #pragma unroll
            for (int rf = 0; rf < 4; rf++)
                a[rf] = *(const v8h*)&sA[cur][(rh * 8 + kh * 4 + rf) * 512 + lu];
            #pragma unroll
            for (int j = 0; j < 2; j++)
                bx[j] = *(const v8h*)&sX[cur][((cq * 2 + j) * 2 + kh) * 512 + lu];
            #pragma unroll
            for (int rf = 0; rf < 4; rf++)
                #pragma unroll
                for (int j = 0; j < 2; j++)
                    acc[rf][j] = __builtin_amdgcn_mfma_f32_16x16x32_f16(a[rf], bx[j], acc[rf][j], 0, 0, 0);
        }
        asm volatile("" ::: "memory");
        __builtin_amdgcn_s_barrier();
        asm volatile("" ::: "memory");
        if (kt < 14) STAGE(cur, (kt + 2) * 64);
    }

    #pragma unroll
    for (int rf = 0; rf < 4; rf++)
        #pragma unroll
        for (int j = 0; j < 2; j++) {
            int col = c0 + cq * 32 + j * 16 + l15;
            #pragma unroll
            for (int rr = 0; rr < 4; rr++) {
                int nrow = n0 + rh * 64 + rf * 16 + quad * 4 + rr;
                if (col < 1536) {
                    int tb = col >> 3, f = col & 7;
                    AX[((size_t)tb * NN + nrow) * 32 + g * 8 + f] = f2h(acc[rf][j][rr]);
                } else if (col < 1600) {
                    int cc = col - 1536;
                    Eg[((size_t)(g << 10) + nrow) * 64 + cc] = f2h(acc[rf][j][rr]);
                }
            }
        }
}

// ---------------- Veg[G][g*8+f][c] = W_enc @ W_G(x-block g) ----------------
__global__ void k_veg(const float* __restrict__ W_enc,
                      const float* __restrict__ W_r, const float* __restrict__ W_u,
                      const float* __restrict__ W_c, float* __restrict__ Veg) {
    int idx = blockIdx.x * 256 + threadIdx.x;    // 3*32*64
    int c = idx & 63;
    int gf = (idx >> 6) & 31;
    int G = idx >> 11;
    int g = gf >> 3, f = gf & 7;
    const float* W = (G == 0) ? W_r : ((G == 1) ? W_u : W_c);
    float acc = 0.f;
    for (int c2 = 0; c2 < 64; c2++)
        acc += W_enc[f * HH + c2] * W[(size_t)(g * 128 + c2) * HH + c];
    Veg[idx] = acc;
}

// ---------------- constE[G][n][c] = sum_g (Eg[g][n] + b_enc) @ W_G(x-block g) ----------------
__global__ void k_constE(const unsigned short* __restrict__ Eg, const float* __restrict__ b_enc,
                         const float* __restrict__ W_r, const float* __restrict__ W_u,
                         const float* __restrict__ W_c, float* __restrict__ constE) {
    int G = blockIdx.y;
    int n = blockIdx.x * 4 + (threadIdx.x >> 6);
    int c = threadIdx.x & 63;
    const float* W = (G == 0) ? W_r : ((G == 1) ? W_u : W_c);
    float acc = 0.f;
    for (int g = 0; g < 4; g++)
        for (int c2 = 0; c2 < 64; c2++)
            acc += (h2f(Eg[((size_t)(g << 10) + n) * 64 + c2]) + b_enc[c2]) *
                   W[(size_t)(g * 128 + c2) * HH + c];
    constE[((size_t)G << 16) + (size_t)n * 64 + c] = acc;
}

// ---------------- gate W -> fragment-major: k<32 from Veg, k>=32 from W h-block ----------------
__global__ void k_wfrag2(const float* __restrict__ W, const float* __restrict__ Veg,
                         unsigned short* __restrict__ Wf) {
    int idx = blockIdx.x * 256 + threadIdx.x;   // 4*9*512 = 18432
    int e = idx & 7, l = (idx >> 3) & 63;
    int rest = idx >> 9;
    int ks = rest % 9, cj = rest / 9;
    int c = cj * 16 + (l & 15);
    int k = ks * 32 + (l >> 4) * 8 + e;
    float w;
    if (k < 32) w = Veg[(size_t)k * 64 + c];
    else { int kk = k - 32; int g = kk >> 6, c2 = kk & 63; w = W[(size_t)(g * 128 + 64 + c2) * HH + c]; }
    Wf[idx] = f2h(w);
}
// ---------------- fused output W: Wf_o frag of (W_diff @ W_dec), 6 cj x 10 ks ----------------
__global__ void k_wfragO(const float* __restrict__ W_diff, const float* __restrict__ W_dec,
                         unsigned short* __restrict__ Wf) {
    int idx = blockIdx.x * 256 + threadIdx.x;   // 6*10*512 = 30720
    int e = idx & 7, l = (idx >> 3) & 63;
    int rest = idx >> 9;
    int ks = rest % 10, cj = rest / 10;
    int o = cj * 16 + (l & 15);
    int k = ks * 32 + (l >> 4) * 8 + e;
    float acc = 0.f;
    for (int c = 0; c < 64; c++) acc += W_diff[(size_t)k * HH + c] * W_dec[(size_t)c * ODIM + o];
    Wf[idx] = f2h(acc);
}
__global__ void k_bzd(const float* __restrict__ b_diff, const float* __restrict__ W_dec,
                      const float* __restrict__ b_dec, float* __restrict__ bzd) {
    int o = threadIdx.x;  // 96
    float acc = b_dec[o];
    for (int c = 0; c < 64; c++) acc += b_diff[c] * W_dec[(size_t)c * ODIM + o];
    bzd[o] = acc;
}

// ---------------- h-hop: 128x128 (b-pair) tile, XCD-grouped 1D grid (bid = bp*32 + rt) ----------
__global__ __launch_bounds__(512) void k_hopA(
        const unsigned short* __restrict__ Mf,
        const unsigned short* __restrict__ Xb,
        unsigned short* __restrict__ Yout, int out_stride, int out_gmul, int out_off) {
    int bid = blockIdx.x;
    int rt = bid & 31;          // XCD = bid%8 = rt%8 -> A rows L2-resident per XCD
    int bp = bid >> 5;          // batch pair
    int g = rt >> 3;
    int n0 = (rt & 7) * 128;

    __shared__ unsigned short sA[2][16 * 512];
    __shared__ unsigned short sX[2][16 * 512];

    int tid = threadIdx.x;
    int lane = tid & 63, wave = tid >> 6;
    int rh = wave >> 2, cq = wave & 3;
    int l15 = lane & 15, quad = lane >> 4;

    const unsigned short* Xbase = Xb + (size_t)(bp * 2) * 64 * NN;  // 128 contiguous c-rows

    v4f acc[4][2];
    #pragma unroll
    for (int i = 0; i < 4; i++)
        #pragma unroll
        for (int j = 0; j < 2; j++) { acc[i][j][0]=0.f; acc[i][j][1]=0.f; acc[i][j][2]=0.f; acc[i][j][3]=0.f; }

    auto STAGE = [&](int buf, int k0) {
        #pragma unroll
        for (int s = 0; s < 4; s++) {
            int id = wave + s * 8;
            if (id < 16) {
                int ah = id >> 3, kh = (id >> 2) & 1, rf = id & 3;
                const unsigned short* src = Mf +
                    ((size_t)(rt * 2 + ah) * 8192 +
                     (size_t)((k0 >> 3) + kh * 4 + quad) * 64 + rf * 16 + l15) * 8;
                gl_lds16(src, &sA[buf][id * 512]);
            } else {
                int xi = id - 16, cj = xi >> 1, kh = xi & 1;
                const unsigned short* src = Xbase +
                    (size_t)(cj * 16 + l15) * NN + k0 + kh * 32 + quad * 8;
                gl_lds16(src, &sX[buf][xi * 512]);
            }
        }
    };

    STAGE(0, 0);
    STAGE(1, 64);

    int lu = lane * 8;
    for (int kt = 0; kt < 16; kt++) {
        int cur = kt & 1;
        if (kt < 15) asm volatile("s_waitcnt vmcnt(4)" ::: "memory");
        else         asm volatile("s_waitcnt vmcnt(0)" ::: "memory");
        __builtin_amdgcn_s_barrier();
        asm volatile("" ::: "memory");
        #pragma unroll
        for (int kh = 0; kh < 2; kh++) {
            v8h a[4], bx[2];
            #pragma unroll
            for (int rf = 0; rf < 4; rf++)
                a[rf] = *(const v8h*)&sA[cur][(rh * 8 + kh * 4 + rf) * 512 + lu];
            #pragma unroll
            for (int j = 0; j < 2; j++)
                bx[j] = *(const v8h*)&sX[cur][((cq * 2 + j) * 2 + kh) * 512 + lu];
            #pragma unroll
            for (int rf = 0; rf < 4; rf++)
                #pragma unroll
                for (int j = 0; j < 2; j++)
                    acc[rf][j] = __builtin_amdgcn_mfma_f32_16x16x32_f16(a[rf], bx[j], acc[rf][j], 0, 0, 0);
        }
        asm volatile("" ::: "memory");
        __builtin_amdgcn_s_barrier();
        asm volatile("" ::: "memory");
        if (kt < 14) STAGE(cur, (kt + 2) * 64);
    }

    #pragma unroll
    for (int rf = 0; rf < 4; rf++)
        #pragma unroll
        for (int j = 0; j < 2; j++) {
            int colloc = cq * 32 + j * 16 + l15;       // 0..127
            int b = bp * 2 + (colloc >> 6);
            int c = colloc & 63;
            unsigned short* Y = Yout + (size_t)b * NN * out_stride + out_gmul * g + out_off + c;
            int rbase = n0 + rh * 64 + rf * 16 + quad * 4;
            #pragma unroll
            for (int rr = 0; rr < 4; rr++)
                Y[(size_t)(rbase + rr) * out_stride] = f2h(acc[rf][j][rr]);
        }
}

// ---------------- gates via MFMA: K=288 = [AX(32) | Fh(256)]; rh -> Xh, u -> ubuf ----------------
__global__ __launch_bounds__(256) void k_gatesM(
        const unsigned short* __restrict__ AXt,   // [16][1024][32] (this t)
        const unsigned short* __restrict__ Fh,    // [16384][256]
        const unsigned short* __restrict__ Wf_r, const unsigned short* __restrict__ Wf_u,
        const float* __restrict__ b_r, const float* __restrict__ b_u,
        const float* __restrict__ constE,         // [3][1024][64]
        const float* __restrict__ h,
        unsigned short* __restrict__ Xh, float* __restrict__ ubuf) {
    int row0 = blockIdx.x * 64;
    int b = row0 >> 10, n0g = row0 & 1023;
    int tid = threadIdx.x, lane = tid & 63, wave = tid >> 6;
    int gate = wave >> 1;              // 0 = r, 1 = u
    int rhalf = (wave & 1) * 32;
    int l15 = lane & 15, quad = lane >> 4;
    const unsigned short* Wf = gate ? Wf_u : Wf_r;
    const float* bias = gate ? b_u : b_r;
    const float* cE = constE + ((size_t)gate << 16);

    __shared__ unsigned short sT[64 * 72];

    v4f acc[2][4];
    #pragma unroll
    for (int rf = 0; rf < 2; rf++)
        #pragma unroll
        for (int cj = 0; cj < 4; cj++) { acc[rf][cj][0]=0.f; acc[rf][cj][1]=0.f; acc[rf][cj][2]=0.f; acc[rf][cj][3]=0.f; }

    const unsigned short* ax = AXt + ((size_t)b * NN + n0g + rhalf + l15) * 32 + quad * 8;
    const unsigned short* fh = Fh + (size_t)(row0 + rhalf + l15) * 256 + quad * 8;
    {
        v8h a0 = *(const v8h*)ax;
        v8h a1 = *(const v8h*)(ax + 16 * 32);
        #pragma unroll
        for (int cj = 0; cj < 4; cj++) {
            v8h bf = *(const v8h*)(Wf + (size_t)(cj * 9) * 512 + lane * 8);
            acc[0][cj] = __builtin_amdgcn_mfma_f32_16x16x32_f16(a0, bf, acc[0][cj], 0, 0, 0);
            acc[1][cj] = __builtin_amdgcn_mfma_f32_16x16x32_f16(a1, bf, acc[1][cj], 0, 0, 0);
        }
    }
    #pragma unroll
    for (int ks = 1; ks < 9; ks++) {
        v8h a0 = *(const v8h*)(fh + (ks - 1) * 32);
        v8h a1 = *(const v8h*)(fh + 16 * 256 + (ks - 1) * 32);
        #pragma unroll
        for (int cj = 0; cj < 4; cj++) {
            v8h bf = *(const v8h*)(Wf + (size_t)(cj * 9 + ks) * 512 + lane * 8);
            acc[0][cj] = __builtin_amdgcn_mfma_f32_16x16x32_f16(a0, bf, acc[0][cj], 0, 0, 0);
            acc[1][cj] = __builtin_amdgcn_mfma_f32_16x16x32_f16(a1, bf, acc[1][cj], 0, 0, 0);
        }
    }

    if (gate == 0) {
        #pragma unroll
        for (int rf = 0; rf < 2; rf++)
            #pragma unroll
            for (int cj = 0; cj < 4; cj++) {
                int c = cj * 16 + l15;
                float bb = bias[c];
                #pragma unroll
                for (int rr = 0; rr < 4; rr++) {
                    int nloc = rhalf + rf * 16 + quad * 4 + rr;
                    float pre = acc[rf][cj][rr] + bb + cE[(size_t)(n0g + nloc) * 64 + c];
                    float r = 1.f / (1.f + expf(-pre));
                    sT[c * 72 + nloc] = f2h(r * h[(size_t)(row0 + nloc) * HH + c]);
                }
            }
    } else {
        #pragma unroll
        for (int rf = 0; rf < 2; rf++)
            #pragma unroll
            for (int cj = 0; cj < 4; cj++) {
                int c = cj * 16 + l15;
                float bb = bias[c];
                #pragma unroll
                for (int rr = 0; rr < 4; rr++) {
                    int nloc = rhalf + rf * 16 + quad * 4 + rr;
                    float pre = acc[rf][cj][rr] + bb + cE[(size_t)(n0g + nloc) * 64 + c];
                    float u = 1.f / (1.f + expf(-pre));
                    ubuf[(size_t)(row0 + nloc) * HH + c] = u;
                }
            }
    }
    __syncthreads();
    #pragma unroll
    for (int i = 0; i < 2; i++) {
        int ii = tid * 2 + i;
        int c = ii >> 3, n8 = (ii & 7) * 8;
        *(uint4*)(Xh + ((size_t)b * 64 + c) * NN + n0g + n8) = *(uint4*)&sT[c * 72 + n8];
    }
}

// ---------------- candidate via MFMA (K=288) + h update; new h -> h f32 AND Xh fp16 --------------
__global__ __launch_bounds__(256) void k_candM(
        const unsigned short* __restrict__ AXt,
        const unsigned short* __restrict__ Fh,
        const unsigned short* __restrict__ Wf_c, const float* __restrict__ b_c,
        const float* __restrict__ constE,
        const float* __restrict__ ubuf,
        float* __restrict__ h, unsigned short* __restrict__ Xh) {
    int row0 = blockIdx.x * 64;
    int b = row0 >> 10, n0g = row0 & 1023;
    int tid = threadIdx.x, lane = tid & 63, wave = tid >> 6;
    int l15 = lane & 15, quad = lane >> 4;
    const float* cE = constE + ((size_t)2 << 16);

    __shared__ unsigned short sT[64 * 72];

    v4f acc[4];
    #pragma unroll
    for (int cj = 0; cj < 4; cj++) { acc[cj][0]=0.f; acc[cj][1]=0.f; acc[cj][2]=0.f; acc[cj][3]=0.f; }

    const unsigned short* ax = AXt + ((size_t)b * NN + n0g + wave * 16 + l15) * 32 + quad * 8;
    const unsigned short* fh = Fh + (size_t)(row0 + wave * 16 + l15) * 256 + quad * 8;
    {
        v8h a = *(const v8h*)ax;
        #pragma unroll
        for (int cj = 0; cj < 4; cj++) {
            v8h bf = *(const v8h*)(Wf_c + (size_t)(cj * 9) * 512 + lane * 8);
            acc[cj] = __builtin_amdgcn_mfma_f32_16x16x32_f16(a, bf, acc[cj], 0, 0, 0);
        }
    }
    #pragma unroll
    for (int ks = 1; ks < 9; ks++) {
        v8h a = *(const v8h*)(fh + (ks - 1) * 32);
        #pragma unroll
        for (int cj = 0; cj < 4; cj++) {
            v8h bf = *(const v8h*)(Wf_c + (size_t)(cj * 9 + ks) * 512 + lane * 8);
            acc[cj] = __builtin_amdgcn_mfma_f32_16x16x32_f16(a, bf, acc[cj], 0, 0, 0);
        }
    }

    #pragma unroll
    for (int cj = 0; cj < 4; cj++) {
        int c = cj * 16 + l15;
        float bb = b_c[c];
        #pragma unroll
        for (int rr = 0; rr < 4; rr++) {
            int nloc = wave * 16 + quad * 4 + rr;
            size_t o = (size_t)(row0 + nloc) * HH + c;
            float pre = acc[cj][rr] + bb + cE[(size_t)(n0g + nloc) * 64 + c];
            float cv = tanhf(pre);
            float u = ubuf[o];
            float hv = h[o];
            float hn = u * hv + (1.f - u) * cv;
            h[o] = hn;
            sT[c * 72 + nloc] = f2h(hn);
        }
    }
    __syncthreads();
    #pragma unroll
    for (int i = 0; i < 2; i++) {
        int ii = tid * 2 + i;
        int c = ii >> 3, n8 = (ii & 7) * 8;
        *(uint4*)(Xh + ((size_t)b * 64 + c) * NN + n0g + n8) = *(uint4*)&sT[c * 72 + n8];
    }
}

// ---------------- out = featd @ (W_diff@W_dec) + bzd, scattered to [b][t][n][f] ----------------
__global__ __launch_bounds__(256) void k_out(
        const unsigned short* __restrict__ featd,
        const unsigned short* __restrict__ Wf_o, const float* __restrict__ bzd,
        float* __restrict__ out) {
    int row0 = blockIdx.x * 64;
    int tid = threadIdx.x, lane = tid & 63, wave = tid >> 6;
    int l15 = lane & 15, quad = lane >> 4;

    v4f acc[6];
    #pragma unroll
    for (int cj = 0; cj < 6; cj++) { acc[cj][0]=0.f; acc[cj][1]=0.f; acc[cj][2]=0.f; acc[cj][3]=0.f; }

    const unsigned short* fbase = featd + (size_t)(row0 + wave * 16 + l15) * DIN + quad * 8;
    #pragma unroll 2
    for (int ks = 0; ks < 10; ks++) {
        v8h a = *(const v8h*)(fbase + ks * 32);
        #pragma unroll
        for (int cj = 0; cj < 6; cj++) {
            v8h bf = *(const v8h*)(Wf_o + (size_t)(cj * 10 + ks) * 512 + lane * 8);
            acc[cj] = __builtin_amdgcn_mfma_f32_16x16x32_f16(a, bf, acc[cj], 0, 0, 0);
        }
    }
    #pragma unroll
    for (int cj = 0; cj < 6; cj++) {
        int o = cj * 16 + l15;
        int t = o >> 3, f = o & 7;
        float bb = bzd[o];
        #pragma unroll
        for (int rr = 0; rr < 4; rr++) {
            int row = row0 + wave * 16 + quad * 4 + rr;
            int b = row >> 10, n = row & 1023;
            out[(((size_t)b * TT + t) * NN + n) * FF + f] = acc[cj][rr] + bb;
        }
    }
}

// ---------------- DiffConv operator build ----------------
__global__ void k_deg(const int* __restrict__ ei32, const float* __restrict__ ew,
                      float* __restrict__ degd, float* __restrict__ degs) {
    int e = blockIdx.x * 256 + threadIdx.x;
    float w = ew[e];
    atomicAdd(&degd[ei32[EE + e]], w);
    atomicAdd(&degs[ei32[e]], w);
}
__global__ void k_spadd(const int* __restrict__ ei32, const float* __restrict__ ew,
                        const float* __restrict__ degd, const float* __restrict__ degs,
                        float* __restrict__ temp) {
    int e = blockIdx.x * 256 + threadIdx.x;
    int s = ei32[e], d = ei32[EE + e];
    float w = ew[e];
    float dd = degd[d], ds = degs[s];
    float wfv = dd > 0.f ? w / dd : 0.f;
    float wbv = ds > 0.f ? w / ds : 0.f;
    atomicAdd(&temp[(size_t)d * NN + s], wfv);
    atomicAdd(&temp[(size_t)NN * NN + (size_t)s * NN + d], wbv);
}
__global__ void k_spconv(const float* __restrict__ temp, unsigned short* __restrict__ Mp) {
    size_t i0 = ((size_t)blockIdx.x * 256 + threadIdx.x) * 8;
    size_t dst = (i0 < (size_t)NN * NN) ? i0 : i0 + (size_t)NN * NN;
    unsigned short h8[8];
    #pragma unroll
    for (int j = 0; j < 8; j++) h8[j] = f2h(temp[i0 + j]);
    *(uint4*)(Mp + dst) = *(uint4*)h8;
}

__global__ void k_featd_h(const float* __restrict__ h, unsigned short* __restrict__ featd) {
    size_t idx = (size_t)blockIdx.x * 256 + threadIdx.x;
    size_t row = idx >> 6; int c = (int)(idx & 63);
    featd[row * DIN + c] = f2h(h[idx]);
}

extern "C" void kernel_launch(void* const* d_in, const int* in_sizes, int n_in,
                              void* d_out, int out_size, void* d_ws, size_t ws_size,
                              hipStream_t stream) {
    const float* x      = (const float*)d_in[0];
    const int*   eiraw  = (const int*)  d_in[1];
    const float* ew     = (const float*)d_in[2];
    const float* adj    = (const float*)d_in[3];
    const float* W_enc  = (const float*)d_in[4];
    const float* b_enc  = (const float*)d_in[5];
    const float* emb    = (const float*)d_in[6];
    const float* W_r    = (const float*)d_in[7];
    const float* b_r    = (const float*)d_in[8];
    const float* W_u    = (const float*)d_in[9];
    const float* b_u    = (const float*)d_in[10];
    const float* W_c    = (const float*)d_in[11];
    const float* b_c    = (const float*)d_in[12];
    const float* W_diff = (const float*)d_in[13];
    const float* b_diff = (const float*)d_in[14];
    const float* W_dec  = (const float*)d_in[15];
    const float* b_dec  = (const float*)d_in[16];

    // ---- workspace ~53 MiB ----
    unsigned short* Mf    = (unsigned short*)d_ws;            // 8 MiB
    unsigned short* Xh    = Mf + (size_t)4096 * NN;           // 2 MiB
    unsigned short* FD    = Xh + (size_t)BB * 64 * NN;        // 10 MiB: featd [16384][320]; Fh overlay
    unsigned short* Fh    = FD;                               //   [16384][256]
    unsigned short* featd = FD;
    float* h    = (float*)(FD + (size_t)BB * NN * DIN);       // 4 MiB
    float* ubuf = h + (size_t)BB * NN * HH;                   // 4 MiB
    unsigned short* AXall = (unsigned short*)(ubuf + (size_t)BB * NN * HH); // 12 MiB [tb][n][32]
    unsigned short* Mp    = AXall;                            // 8 MiB overlay (prep & readout)
    unsigned short* XallT = AXall + (size_t)192 * NN * 32;    // 3.125 MiB [1600][1024]
    unsigned short* Eg    = XallT + (size_t)1600 * NN;        // 0.5 MiB [4][1024][64]
    float* sptmp  = (float*)(Eg + (size_t)4 * NN * 64);       // 8 MiB
    float* constE = sptmp + (size_t)2 * NN * NN;              // 768 KiB [3][1024][64]
    float* Veg    = constE + (size_t)3 * NN * 64;             // 24 KiB [3][32][64]
    unsigned short* Wf_r = (unsigned short*)(Veg + 3 * 32 * 64);
    unsigned short* Wf_u = Wf_r + 4 * 9 * 512;
    unsigned short* Wf_c = Wf_u + 4 * 9 * 512;
    unsigned short* Wf_o = Wf_c + 4 * 9 * 512;                // 6*10*512 = 30720
    float* bzd  = (float*)(Wf_o + 30720);
    float* rinv = bzd + ODIM;
    float* cinv = rinv + NN;
    int*   eifl = (int*)(cinv + NN);
    int*   ei32 = eifl + 4;
    float* degd = (float*)(ei32 + 2 * EE);
    float* degs = degd + NN;

    hipMemsetAsync(h, 0, (size_t)BB * NN * HH * 4, stream);
    hipMemsetAsync(Xh, 0, (size_t)BB * 64 * NN * 2, stream);   // h = 0 at t=0

    // ---- build plain M = [Af; Af^2; Ab; Ab^2] (fp16), convert to fragment-major ----
    k_rowsum<<<NN, 256, 0, stream>>>(adj, rinv);
    k_colsum<<<NN / 256, 256, 0, stream>>>(adj, cinv);
    k_prepA<<<dim3(16, 16), 256, 0, stream>>>(adj, rinv, cinv, Mp);
    k_msq<<<dim3(16, 16, 2), 256, 0, stream>>>(Mp);
    k_m2frag<<<2048, 256, 0, stream>>>(Mp, Mf);

    // ---- x/emb transposes, batched x-hop (overwrites Mp region), const folds ----
    k_xT<<<TT * BB, 256, 0, stream>>>(x, XallT);
    k_embT<<<64, 256, 0, stream>>>(emb, XallT);
    k_hopX<<<13 * 32, 512, 0, stream>>>(Mf, XallT, AXall, Eg);
    k_veg<<<24, 256, 0, stream>>>(W_enc, W_r, W_u, W_c, Veg);
    k_constE<<<dim3(256, 3), 256, 0, stream>>>(Eg, b_enc, W_r, W_u, W_c, constE);
    k_wfrag2<<<72, 256, 0, stream>>>(W_r, Veg, Wf_r);
    k_wfrag2<<<72, 256, 0, stream>>>(W_u, Veg + 2048, Wf_u);
    k_wfrag2<<<72, 256, 0, stream>>>(W_c, Veg + 4096, Wf_c);
    k_wfragO<<<120, 256, 0, stream>>>(W_diff, W_dec, Wf_o);
    k_bzd<<<1, ODIM, 0, stream>>>(b_diff, W_dec, b_dec, bzd);

    for (int t = 0; t < TT; t++) {
        const unsigned short* AXt = AXall + (size_t)t * BB * NN * 32;
        // 4 operators @ h -> Fh [row][g*64+c]
        k_hopA<<<8 * 32, 512, 0, stream>>>(Mf, Xh, Fh, 256, 64, 0);
        // gates: rh -> Xh (fp16), u -> ubuf (f32)
        k_gatesM<<<BB * NN / 64, 256, 0, stream>>>(AXt, Fh, Wf_r, Wf_u, b_r, b_u, constE, h, Xh, ubuf);
        // 4 operators @ rh -> Fh
        k_hopA<<<8 * 32, 512, 0, stream>>>(Mf, Xh, Fh, 256, 64, 0);
        // candidate + h update
        k_candM<<<BB * NN / 64, 256, 0, stream>>>(AXt, Fh, Wf_c, b_c, constE, ubuf, h, Xh);
    }

    // ---- DiffConv readout ----
    k_ei_detect<<<1, 256, 0, stream>>>(eiraw, eifl);
    k_ei_norm<<<2 * EE / 256, 256, 0, stream>>>(eiraw, eifl, ei32);
    hipMemsetAsync(degd, 0, (size_t)2 * NN * 4, stream);
    hipMemsetAsync(sptmp, 0, (size_t)2 * NN * NN * 4, stream);
    k_deg<<<EE / 256, 256, 0, stream>>>(ei32, ew, degd, degs);
    k_spadd<<<EE / 256, 256, 0, stream>>>(ei32, ew, degd, degs, sptmp);
    k_spconv<<<2 * NN * NN / (256 * 8), 256, 0, stream>>>(sptmp, Mp);
    k_msq<<<dim3(16, 16, 2), 256, 0, stream>>>(Mp);
    k_m2frag<<<2048, 256, 0, stream>>>(Mp, Mf);
    k_featd_h<<<BB * NN * HH / 256, 256, 0, stream>>>(h, featd);
    // [Sf;Sf2;Sb;Sb2] @ h (fp16 in Xh) -> featd cols 64 + g*64
    k_hopA<<<8 * 32, 512, 0, stream>>>(Mf, Xh, featd, DIN, 64, 64);
    k_out<<<BB * NN / 64, 256, 0, stream>>>(featd, Wf_o, bzd, (float*)d_out);
}

// Round 8
// 722.522 us; speedup vs baseline: 1.5558x; 1.3824x over previous
//
#include <hip/hip_runtime.h>
#include <math.h>

#define BB 16
#define TT 12
#define NN 1024
#define FF 8
#define HH 64
#define EE 32768
#define DIN 320   // H * (2K+1)
#define ODIM 96   // F * HORIZON
#define APAD 40   // k_msq LDS row stride

typedef _Float16 v8h __attribute__((ext_vector_type(8)));
typedef float v4f __attribute__((ext_vector_type(4)));

__device__ __forceinline__ unsigned short f2h(float v) {
    _Float16 h = (_Float16)v;          // RNE v_cvt_f16_f32
    unsigned short u;
    __builtin_memcpy(&u, &h, 2);
    return u;
}
__device__ __forceinline__ float h2f(unsigned short u) {
    _Float16 h;
    __builtin_memcpy(&h, &u, 2);
    return (float)h;
}
// async global->LDS, 16B per lane; LDS dst = wave-uniform base + lane*16
__device__ __forceinline__ void gl_lds16(const void* g, void* l) {
    __builtin_amdgcn_global_load_lds(
        (const __attribute__((address_space(1))) unsigned int*)g,
        (__attribute__((address_space(3))) unsigned int*)l, 16, 0, 0);
}

// ---------------- edge_index insurance ----------------
__global__ void k_ei_detect(const int* __restrict__ ei_raw, int* __restrict__ flag) {
    __shared__ int s[256];
    s[threadIdx.x] = ei_raw[2 * threadIdx.x + 1];
    __syncthreads();
    for (int st = 128; st > 0; st >>= 1) {
        if (threadIdx.x < st) s[threadIdx.x] |= s[threadIdx.x + st];
        __syncthreads();
    }
    if (threadIdx.x == 0) flag[0] = (s[0] == 0) ? 1 : 0;
}
__global__ void k_ei_norm(const int* __restrict__ ei_raw, const int* __restrict__ flag,
                          int* __restrict__ ei32) {
    int j = blockIdx.x * 256 + threadIdx.x;
    ei32[j] = flag[0] ? ei_raw[2 * j] : ei_raw[j];
}

// ---------------- support normalization ----------------
__global__ void k_rowsum(const float* __restrict__ adj, float* __restrict__ rinv) {
    __shared__ float s[256];
    int i = blockIdx.x;
    float acc = 0.f;
    for (int j = threadIdx.x; j < NN; j += 256) acc += adj[i * NN + j];
    s[threadIdx.x] = acc;
    __syncthreads();
    for (int st = 128; st > 0; st >>= 1) {
        if (threadIdx.x < st) s[threadIdx.x] += s[threadIdx.x + st];
        __syncthreads();
    }
    if (threadIdx.x == 0) rinv[i] = (s[0] != 0.f) ? 1.f / s[0] : 0.f;
}
__global__ void k_colsum(const float* __restrict__ adj, float* __restrict__ cinv) {
    int j = blockIdx.x * 256 + threadIdx.x;
    float acc = 0.f;
    for (int i = 0; i < NN; i++) acc += adj[i * NN + j];
    cinv[j] = (acc != 0.f) ? 1.f / acc : 0.f;
}

// ---------------- Af -> plain rows 0..1023, Ab -> plain rows 2048..3071 (single fp16) ----------------
__global__ __launch_bounds__(256) void k_prepA(
        const float* __restrict__ adj, const float* __restrict__ rinv,
        const float* __restrict__ cinv, unsigned short* __restrict__ Mp) {
    int w0 = blockIdx.x * 64, v0 = blockIdx.y * 64;
    __shared__ float T[64][68];
    int row = threadIdx.x >> 2, cs = (threadIdx.x & 3) * 16;
    #pragma unroll
    for (int j = 0; j < 4; j++)
        *(float4*)&T[row][cs + j * 4] = *(const float4*)(adj + (size_t)(w0 + row) * NN + v0 + cs + j * 4);
    __syncthreads();
    {
        float sc = rinv[w0 + row];
        unsigned short h8[16];
        #pragma unroll
        for (int j = 0; j < 16; j++) h8[j] = f2h(T[row][cs + j] * sc);
        size_t ofs = (size_t)(w0 + row) * NN + v0 + cs;
        ((uint4*)(Mp + ofs))[0] = *(uint4*)&h8[0];
        ((uint4*)(Mp + ofs))[1] = *(uint4*)&h8[8];
    }
    {
        float sc = cinv[v0 + row];
        unsigned short h8[16];
        #pragma unroll
        for (int j = 0; j < 16; j++) h8[j] = f2h(T[cs + j][row] * sc);
        size_t ofs = (size_t)2048 * NN + (size_t)(v0 + row) * NN + w0 + cs;
        ((uint4*)(Mp + ofs))[0] = *(uint4*)&h8[0];
        ((uint4*)(Mp + ofs))[1] = *(uint4*)&h8[8];
    }
}

// ---------------- plain M rows (zz) squared: rows zz*2048 -> zz*2048+1024 ----------------
__global__ __launch_bounds__(256) void k_msq(unsigned short* __restrict__ M) {
    int zz = blockIdx.z;
    size_t srcb = (size_t)zz * 2048 * NN;
    size_t dstb = srcb + (size_t)1024 * NN;
    int w0 = blockIdx.x * 64, n0 = blockIdx.y * 64;

    __shared__ unsigned short sA[64 * APAD];
    __shared__ unsigned short sB[64 * APAD];

    int tid = threadIdx.x;
    int lane = tid & 63, wave = tid >> 6;
    int wr = (wave >> 1) * 32, wc = (wave & 1) * 32;
    int l15 = lane & 15, quad = lane >> 4;
    int arow = tid >> 2, akk = (tid & 3) * 8;
    int bkr = tid & 31, bc8 = (tid >> 5) * 8;

    v4f acc[2][2];
    #pragma unroll
    for (int i = 0; i < 2; i++)
        #pragma unroll
        for (int j = 0; j < 2; j++) { acc[i][j][0]=0.f; acc[i][j][1]=0.f; acc[i][j][2]=0.f; acc[i][j][3]=0.f; }

    for (int k0 = 0; k0 < NN; k0 += 32) {
        *(uint4*)&sA[arow * APAD + akk] = *(const uint4*)(M + srcb + (size_t)(w0 + arow) * NN + k0 + akk);
        uint4 bh = *(const uint4*)(M + srcb + (size_t)(k0 + bkr) * NN + n0 + bc8);
        const unsigned short* ph = (const unsigned short*)&bh;
        #pragma unroll
        for (int j = 0; j < 8; j++) sB[(bc8 + j) * APAD + bkr] = ph[j];
        __syncthreads();

        v8h a0 = *(const v8h*)&sA[(wr + l15) * APAD + quad * 8];
        v8h a1 = *(const v8h*)&sA[(wr + 16 + l15) * APAD + quad * 8];
        #pragma unroll
        for (int j = 0; j < 2; j++) {
            v8h bb = *(const v8h*)&sB[(wc + j * 16 + l15) * APAD + quad * 8];
            acc[0][j] = __builtin_amdgcn_mfma_f32_16x16x32_f16(a0, bb, acc[0][j], 0, 0, 0);
            acc[1][j] = __builtin_amdgcn_mfma_f32_16x16x32_f16(a1, bb, acc[1][j], 0, 0, 0);
        }
        __syncthreads();
    }

    #pragma unroll
    for (int i = 0; i < 2; i++)
        #pragma unroll
        for (int j = 0; j < 2; j++) {
            int rb = w0 + wr + i * 16 + quad * 4;
            int cc = n0 + wc + j * 16 + l15;
            #pragma unroll
            for (int rr = 0; rr < 4; rr++)
                M[dstb + (size_t)(rb + rr) * NN + cc] = f2h(acc[i][j][rr]);
        }
}

// ---------------- plain -> fragment-major: chunk t = (T*128 + kc)*64 + rowloc ----------------
__global__ void k_m2frag(const unsigned short* __restrict__ P, unsigned short* __restrict__ F) {
    size_t t = (size_t)blockIdx.x * 256 + threadIdx.x;
    int rowloc = (int)(t & 63);
    int kc = (int)((t >> 6) & 127);
    int T = (int)(t >> 13);
    size_t src = ((size_t)(T * 64 + rowloc) * NN) + kc * 8;
    *(uint4*)(F + t * 8) = *(const uint4*)(P + src);
}

// ---------------- x -> XallT rows: XallT[(t*16+b)*8+f][n] fp16 ----------------
__global__ void k_xT(const float* __restrict__ x, unsigned short* __restrict__ XallT) {
    int bx = blockIdx.x;            // t*16+b
    int t = bx >> 4, b = bx & 15;
    int tid = threadIdx.x;
    int f = tid & 7, half = tid >> 3;   // half 0..31
    const float* xs = x + ((size_t)b * TT + t) * NN * FF + f;
    int n0 = half * 32;
    unsigned short v[32];
    #pragma unroll
    for (int i = 0; i < 32; i++) v[i] = f2h(xs[(size_t)(n0 + i) * FF]);
    unsigned short* dst = XallT + ((size_t)bx * 8 + f) * NN + n0;
    #pragma unroll
    for (int i = 0; i < 4; i++) *(uint4*)(dst + i * 8) = *(uint4*)&v[i * 8];
}
// ---------------- emb -> XallT rows 1536..1599: embT[c][n] ----------------
__global__ void k_embT(const float* __restrict__ emb, unsigned short* __restrict__ XallT) {
    int c = blockIdx.x;
    int n0 = threadIdx.x * 4;
    unsigned short v[4];
    #pragma unroll
    for (int j = 0; j < 4; j++) v[j] = f2h(emb[(size_t)(n0 + j) * HH + c]);
    *(uint2*)(XallT + (size_t)(1536 + c) * NN + n0) = *(uint2*)v;
}

// ---------------- batched x-hop: 128x128 tile, XCD-grouped 1D grid (bid = y*32 + rt) ------------
__global__ __launch_bounds__(512) void k_hopX(
        const unsigned short* __restrict__ Mf,
        const unsigned short* __restrict__ XallT,
        unsigned short* __restrict__ AX, unsigned short* __restrict__ Eg) {
    int bid = blockIdx.x;
    int rt = bid & 31;          // XCD = bid%8 = rt%8 -> same-rt blocks share an XCD L2
    int y  = bid >> 5;
    int g = rt >> 3;
    int n0 = (rt & 7) * 128;
    int c0 = y * 128;

    __shared__ unsigned short sA[2][16 * 512];
    __shared__ unsigned short sX[2][16 * 512];

    int tid = threadIdx.x;
    int lane = tid & 63, wave = tid >> 6;   // 8 waves
    int rh = wave >> 2, cq = wave & 3;      // 2 row-halves x 4 col-quarters
    int l15 = lane & 15, quad = lane >> 4;

    v4f acc[4][2];
    #pragma unroll
    for (int i = 0; i < 4; i++)
        #pragma unroll
        for (int j = 0; j < 2; j++) { acc[i][j][0]=0.f; acc[i][j][1]=0.f; acc[i][j][2]=0.f; acc[i][j][3]=0.f; }

    auto STAGE = [&](int buf, int k0) {
        #pragma unroll
        for (int s = 0; s < 4; s++) {
            int id = wave + s * 8;
            if (id < 16) {
                int ah = id >> 3, kh = (id >> 2) & 1, rf = id & 3;
                const unsigned short* src = Mf +
                    ((size_t)(rt * 2 + ah) * 8192 +
                     (size_t)((k0 >> 3) + kh * 4 + quad) * 64 + rf * 16 + l15) * 8;
                gl_lds16(src, &sA[buf][id * 512]);
            } else {
                int xi = id - 16, cj = xi >> 1, kh = xi & 1;
                const unsigned short* src = XallT +
                    (size_t)(c0 + cj * 16 + l15) * NN + k0 + kh * 32 + quad * 8;
                gl_lds16(src, &sX[buf][xi * 512]);
            }
        }
    };

    STAGE(0, 0);
    STAGE(1, 64);

    int lu = lane * 8;
    for (int kt = 0; kt < 16; kt++) {
        int cur = kt & 1;
        if (kt < 15) asm volatile("s_waitcnt vmcnt(4)" ::: "memory");
        else         asm volatile("s_waitcnt vmcnt(0)" ::: "memory");
        __builtin_amdgcn_s_barrier();
        asm volatile("" ::: "memory");
        #pragma unroll
        for (int kh = 0; kh < 2; kh++) {
            v8h a[4], bx[2];
            #pragma unroll
            for (int rf = 0; rf < 4; rf++)
                a[rf] = *(const v8h*)&sA[cur][(rh * 8 + kh * 4 + rf) * 512 + lu];
            #pragma unroll
            for (int j = 0; j < 2; j++)
                bx[j] = *(const v8h*)&sX[cur][((cq * 2 + j) * 2 + kh) * 512 + lu];
            #pragma unroll
            for (int rf = 0; rf < 4; rf++)
                #pragma unroll
                for (int j = 0; j < 2; j++)
                    acc[rf][j] = __builtin_amdgcn_mfma_f32_16x16x32_f16(a[rf], bx[j], acc[rf][j], 0, 0, 0);
        }
        asm volatile("" ::: "memory");
        __builtin_amdgcn_s_barrier();
        asm volatile("" ::: "memory");
        if (kt < 14) STAGE(cur, (kt + 2) * 64);
    }

    #pragma unroll
    for (int rf = 0; rf < 4; rf++)
        #pragma unroll
        for (int j = 0; j < 2; j++) {
            int col = c0 + cq * 32 + j * 16 + l15;
            #pragma unroll
            for (int rr = 0; rr < 4; rr++) {
                int nrow = n0 + rh * 64 + rf * 16 + quad * 4 + rr;
                if (col < 1536) {
                    int tb = col >> 3, f = col & 7;
                    AX[((size_t)tb * NN + nrow) * 32 + g * 8 + f] = f2h(acc[rf][j][rr]);
                } else if (col < 1600) {
                    int cc = col - 1536;
                    Eg[((size_t)(g << 10) + nrow) * 64 + cc] = f2h(acc[rf][j][rr]);
                }
            }
        }
}

// ---------------- Veg[G][g*8+f][c] = W_enc @ W_G(x-block g) ----------------
__global__ void k_veg(const float* __restrict__ W_enc,
                      const float* __restrict__ W_r, const float* __restrict__ W_u,
                      const float* __restrict__ W_c, float* __restrict__ Veg) {
    int idx = blockIdx.x * 256 + threadIdx.x;    // 3*32*64
    int c = idx & 63;
    int gf = (idx >> 6) & 31;
    int G = idx >> 11;
    int g = gf >> 3, f = gf & 7;
    const float* W = (G == 0) ? W_r : ((G == 1) ? W_u : W_c);
    float acc = 0.f;
    for (int c2 = 0; c2 < 64; c2++)
        acc += W_enc[f * HH + c2] * W[(size_t)(g * 128 + c2) * HH + c];
    Veg[idx] = acc;
}

// ---------------- constE[G][n][c] = sum_g (Eg[g][n] + b_enc) @ W_G(x-block g) ----------------
__global__ void k_constE(const unsigned short* __restrict__ Eg, const float* __restrict__ b_enc,
                         const float* __restrict__ W_r, const float* __restrict__ W_u,
                         const float* __restrict__ W_c, float* __restrict__ constE) {
    int G = blockIdx.y;
    int n = blockIdx.x * 4 + (threadIdx.x >> 6);
    int c = threadIdx.x & 63;
    const float* W = (G == 0) ? W_r : ((G == 1) ? W_u : W_c);
    float acc = 0.f;
    for (int g = 0; g < 4; g++)
        for (int c2 = 0; c2 < 64; c2++)
            acc += (h2f(Eg[((size_t)(g << 10) + n) * 64 + c2]) + b_enc[c2]) *
                   W[(size_t)(g * 128 + c2) * HH + c];
    constE[((size_t)G << 16) + (size_t)n * 64 + c] = acc;
}

// ---------------- W h-block -> fold fragments: [G][cj*8+ks][512] ----------------
__global__ void k_wfragH(const float* __restrict__ W_r, const float* __restrict__ W_u,
                         const float* __restrict__ W_c,
                         unsigned short* __restrict__ Fr, unsigned short* __restrict__ Fu,
                         unsigned short* __restrict__ Fc) {
    int idx = blockIdx.x * 256 + threadIdx.x;   // 3 * 16384
    int G = idx >> 14;
    int r = idx & 16383;
    int e = r & 7, l = (r >> 3) & 63;
    int rest = r >> 9;                          // cj*8 + ks
    int ks = rest & 7, cj = rest >> 3;
    int c = cj * 16 + (l & 15);
    int k = ks * 32 + (l >> 4) * 8 + e;
    int g = k >> 6, c2 = k & 63;
    const float* W = (G == 0) ? W_r : ((G == 1) ? W_u : W_c);
    unsigned short* F = (G == 0) ? Fr : ((G == 1) ? Fu : Fc);
    F[r] = f2h(W[(size_t)(g * 128 + 64 + c2) * HH + c]);
}
// ---------------- Veg -> x-fold fragments: [G][cj][512] ----------------
__global__ void k_wfragX(const float* __restrict__ Veg, unsigned short* __restrict__ Wx) {
    int idx = blockIdx.x * 256 + threadIdx.x;   // 3 * 2048
    int G = idx >> 11;
    int r = idx & 2047;
    int e = r & 7, l = (r >> 3) & 63;
    int cj = r >> 9;
    int c = cj * 16 + (l & 15);
    int k = (l >> 4) * 8 + e;
    Wx[idx] = f2h(Veg[(size_t)G * 2048 + (size_t)k * 64 + c]);
}

// ---------------- fused output W: Wf_o frag of (W_diff @ W_dec), 6 cj x 10 ks ----------------
__global__ void k_wfragO(const float* __restrict__ W_diff, const float* __restrict__ W_dec,
                         unsigned short* __restrict__ Wf) {
    int idx = blockIdx.x * 256 + threadIdx.x;   // 6*10*512 = 30720
    int e = idx & 7, l = (idx >> 3) & 63;
    int rest = idx >> 9;
    int ks = rest % 10, cj = rest / 10;
    int o = cj * 16 + (l & 15);
    int k = ks * 32 + (l >> 4) * 8 + e;
    float acc = 0.f;
    for (int c = 0; c < 64; c++) acc += W_diff[(size_t)k * HH + c] * W_dec[(size_t)c * ODIM + o];
    Wf[idx] = f2h(acc);
}
__global__ void k_bzd(const float* __restrict__ b_diff, const float* __restrict__ W_dec,
                      const float* __restrict__ b_dec, float* __restrict__ bzd) {
    int o = threadIdx.x;  // 96
    float acc = b_dec[o];
    for (int c = 0; c < 64; c++) acc += b_diff[c] * W_dec[(size_t)c * ODIM + o];
    bzd[o] = acc;
}

// ================= fused hop+gates: 64 rows x 4 ops x 1 batch, fold -> r,u =================
__global__ __launch_bounds__(512) void k_hopRU(
        const unsigned short* __restrict__ Mf,
        const unsigned short* __restrict__ XhH,   // h fp16 [b][64][n]
        const unsigned short* __restrict__ AXt,   // [b][1024][32]
        const unsigned short* __restrict__ WfrH, const unsigned short* __restrict__ WfuH,
        const unsigned short* __restrict__ Wxr, const unsigned short* __restrict__ Wxu,
        const float* __restrict__ b_r, const float* __restrict__ b_u,
        const float* __restrict__ constE,
        const float* __restrict__ h,
        unsigned short* __restrict__ XhR, float* __restrict__ ubuf) {
    int bid = blockIdx.x;
    int b = bid >> 4, nt = bid & 15;   // XCD = nt%8: A rows L2-resident per XCD
    int n0 = nt * 64;

    __shared__ unsigned short S[2][40 * 512];   // 80 KiB

    int tid = threadIdx.x;
    int lane = tid & 63, wave = tid >> 6;
    int l15 = lane & 15, quad = lane >> 4;
    int g = wave >> 1, rh2 = wave & 1;

    const unsigned short* Xbase = XhH + (size_t)b * 64 * NN;

    v4f acc[2][4];
    #pragma unroll
    for (int i = 0; i < 2; i++)
        #pragma unroll
        for (int j = 0; j < 4; j++) { acc[i][j][0]=0.f; acc[i][j][1]=0.f; acc[i][j][2]=0.f; acc[i][j][3]=0.f; }

    auto STAGE = [&](int buf, int k0) {
        #pragma unroll
        for (int s = 0; s < 5; s++) {
            int id = wave + s * 8;
            if (id < 32) {
                int gg = id >> 3, kh = (id >> 2) & 1, rf = id & 3;
                const unsigned short* src = Mf +
                    ((size_t)(gg * 16 + nt) * 8192 +
                     (size_t)((k0 >> 3) + kh * 4 + quad) * 64 + rf * 16 + l15) * 8;
                gl_lds16(src, &S[buf][id * 512]);
            } else {
                int xi = id - 32, cj = xi >> 1, kh = xi & 1;
                const unsigned short* src = Xbase +
                    (size_t)(cj * 16 + l15) * NN + k0 + kh * 32 + quad * 8;
                gl_lds16(src, &S[buf][(32 + xi) * 512]);
            }
        }
    };

    STAGE(0, 0);
    STAGE(1, 64);

    int lu = lane * 8;
    for (int kt = 0; kt < 16; kt++) {
        int cur = kt & 1;
        if (kt < 15) asm volatile("s_waitcnt vmcnt(5)" ::: "memory");
        else         asm volatile("s_waitcnt vmcnt(0)" ::: "memory");
        __builtin_amdgcn_s_barrier();
        asm volatile("" ::: "memory");
        #pragma unroll
        for (int kh = 0; kh < 2; kh++) {
            v8h a[2], bx[4];
            #pragma unroll
            for (int i = 0; i < 2; i++)
                a[i] = *(const v8h*)&S[cur][(g * 8 + kh * 4 + rh2 * 2 + i) * 512 + lu];
            #pragma unroll
            for (int cj = 0; cj < 4; cj++)
                bx[cj] = *(const v8h*)&S[cur][(32 + cj * 2 + kh) * 512 + lu];
            #pragma unroll
            for (int i = 0; i < 2; i++)
                #pragma unroll
                for (int cj = 0; cj < 4; cj++)
                    acc[i][cj] = __builtin_amdgcn_mfma_f32_16x16x32_f16(a[i], bx[cj], acc[i][cj], 0, 0, 0);
        }
        asm volatile("" ::: "memory");
        __builtin_amdgcn_s_barrier();
        asm volatile("" ::: "memory");
        if (kt < 14) STAGE(cur, (kt + 2) * 64);
    }

    // Yt[64][264] fp16 in S[0]: Y[n-row][g*64 + c2] = (A_g h)[n][c2]
    unsigned short* Yt = &S[0][0];
    #pragma unroll
    for (int i = 0; i < 2; i++)
        #pragma unroll
        for (int cj = 0; cj < 4; cj++) {
            int col = g * 64 + cj * 16 + l15;
            #pragma unroll
            for (int rr = 0; rr < 4; rr++) {
                int row = rh2 * 32 + i * 16 + quad * 4 + rr;
                Yt[row * 264 + col] = f2h(acc[i][cj][rr]);
            }
        }
    __syncthreads();

    // fold: waves = 4 row-groups x {r,u}
    int rw = wave & 3, gate = wave >> 2;
    const unsigned short* WH = gate ? WfuH : WfrH;
    const unsigned short* WX = gate ? Wxu : Wxr;
    const float* bias = gate ? b_u : b_r;
    const float* cE = constE + ((size_t)gate << 16);

    v4f acc2[4];
    #pragma unroll
    for (int cj = 0; cj < 4; cj++) { acc2[cj][0]=0.f; acc2[cj][1]=0.f; acc2[cj][2]=0.f; acc2[cj][3]=0.f; }

    {
        v8h ax = *(const v8h*)(AXt + ((size_t)(b << 10) + n0 + rw * 16 + l15) * 32 + quad * 8);
        #pragma unroll
        for (int cj = 0; cj < 4; cj++) {
            v8h bf = *(const v8h*)(WX + (size_t)cj * 512 + lu);
            acc2[cj] = __builtin_amdgcn_mfma_f32_16x16x32_f16(ax, bf, acc2[cj], 0, 0, 0);
        }
    }
    #pragma unroll
    for (int ks = 0; ks < 8; ks++) {
        v8h a = *(const v8h*)&Yt[(rw * 16 + l15) * 264 + ks * 32 + quad * 8];
        #pragma unroll
        for (int cj = 0; cj < 4; cj++) {
            v8h bf = *(const v8h*)(WH + (size_t)(cj * 8 + ks) * 512 + lu);
            acc2[cj] = __builtin_amdgcn_mfma_f32_16x16x32_f16(a, bf, acc2[cj], 0, 0, 0);
        }
    }

    unsigned short* sT = &S[1][0];   // [64][72]
    if (gate == 0) {
        #pragma unroll
        for (int cj = 0; cj < 4; cj++) {
            int c = cj * 16 + l15;
            float bb = bias[c];
            #pragma unroll
            for (int rr = 0; rr < 4; rr++) {
                int nl = rw * 16 + quad * 4 + rr;
                size_t row = (size_t)(b << 10) + n0 + nl;
                float pre = acc2[cj][rr] + bb + cE[(size_t)(n0 + nl) * 64 + c];
                float r = 1.f / (1.f + expf(-pre));
                sT[c * 72 + nl] = f2h(r * h[row * 64 + c]);
            }
        }
    } else {
        #pragma unroll
        for (int cj = 0; cj < 4; cj++) {
            int c = cj * 16 + l15;
            float bb = bias[c];
            #pragma unroll
            for (int rr = 0; rr < 4; rr++) {
                int nl = rw * 16 + quad * 4 + rr;
                size_t row = (size_t)(b << 10) + n0 + nl;
                float pre = acc2[cj][rr] + bb + cE[(size_t)(n0 + nl) * 64 + c];
                ubuf[row * 64 + c] = 1.f / (1.f + expf(-pre));
            }
        }
    }
    __syncthreads();
    {
        int c = tid >> 3, n8 = (tid & 7) * 8;
        *(uint4*)(XhR + ((size_t)b * 64 + c) * NN + n0 + n8) = *(uint4*)&sT[c * 72 + n8];
    }
}

// ================= fused hop+candidate: fold -> c, h update =================
__global__ __launch_bounds__(512) void k_hopC(
        const unsigned short* __restrict__ Mf,
        const unsigned short* __restrict__ XhR,   // rh fp16 [b][64][n]
        const unsigned short* __restrict__ AXt,
        const unsigned short* __restrict__ WfcH, const unsigned short* __restrict__ Wxc,
        const float* __restrict__ b_c,
        const float* __restrict__ constE,
        const float* __restrict__ ubuf,
        float* __restrict__ h, unsigned short* __restrict__ XhH) {
    int bid = blockIdx.x;
    int b = bid >> 4, nt = bid & 15;
    int n0 = nt * 64;

    __shared__ unsigned short S[2][40 * 512];

    int tid = threadIdx.x;
    int lane = tid & 63, wave = tid >> 6;
    int l15 = lane & 15, quad = lane >> 4;
    int g = wave >> 1, rh2 = wave & 1;

    const unsigned short* Xbase = XhR + (size_t)b * 64 * NN;

    v4f acc[2][4];
    #pragma unroll
    for (int i = 0; i < 2; i++)
        #pragma unroll
        for (int j = 0; j < 4; j++) { acc[i][j][0]=0.f; acc[i][j][1]=0.f; acc[i][j][2]=0.f; acc[i][j][3]=0.f; }

    auto STAGE = [&](int buf, int k0) {
        #pragma unroll
        for (int s = 0; s < 5; s++) {
            int id = wave + s * 8;
            if (id < 32) {
                int gg = id >> 3, kh = (id >> 2) & 1, rf = id & 3;
                const unsigned short* src = Mf +
                    ((size_t)(gg * 16 + nt) * 8192 +
                     (size_t)((k0 >> 3) + kh * 4 + quad) * 64 + rf * 16 + l15) * 8;
                gl_lds16(src, &S[buf][id * 512]);
            } else {
                int xi = id - 32, cj = xi >> 1, kh = xi & 1;
                const unsigned short* src = Xbase +
                    (size_t)(cj * 16 + l15) * NN + k0 + kh * 32 + quad * 8;
                gl_lds16(src, &S[buf][(32 + xi) * 512]);
            }
        }
    };

    STAGE(0, 0);
    STAGE(1, 64);

    int lu = lane * 8;
    for (int kt = 0; kt < 16; kt++) {
        int cur = kt & 1;
        if (kt < 15) asm volatile("s_waitcnt vmcnt(5)" ::: "memory");
        else         asm volatile("s_waitcnt vmcnt(0)" ::: "memory");
        __builtin_amdgcn_s_barrier();
        asm volatile("" ::: "memory");
        #pragma unroll
        for (int kh = 0; kh < 2; kh++) {
            v8h a[2], bx[4];
            #pragma unroll
            for (int i = 0; i < 2; i++)
                a[i] = *(const v8h*)&S[cur][(g * 8 + kh * 4 + rh2 * 2 + i) * 512 + lu];
            #pragma unroll
            for (int cj = 0; cj < 4; cj++)
                bx[cj] = *(const v8h*)&S[cur][(32 + cj * 2 + kh) * 512 + lu];
            #pragma unroll
            for (int i = 0; i < 2; i++)
                #pragma unroll
                for (int cj = 0; cj < 4; cj++)
                    acc[i][cj] = __builtin_amdgcn_mfma_f32_16x16x32_f16(a[i], bx[cj], acc[i][cj], 0, 0, 0);
        }
        asm volatile("" ::: "memory");
        __builtin_amdgcn_s_barrier();
        asm volatile("" ::: "memory");
        if (kt < 14) STAGE(cur, (kt + 2) * 64);
    }

    unsigned short* Yt = &S[0][0];
    #pragma unroll
    for (int i = 0; i < 2; i++)
        #pragma unroll
        for (int cj = 0; cj < 4; cj++) {
            int col = g * 64 + cj * 16 + l15;
            #pragma unroll
            for (int rr = 0; rr < 4; rr++) {
                int row = rh2 * 32 + i * 16 + quad * 4 + rr;
                Yt[row * 264 + col] = f2h(acc[i][cj][rr]);
            }
        }
    __syncthreads();

    // fold: waves = 4 row-groups x 2 col-halves
    int rw = wave & 3, ch = wave >> 2;
    const float* cE = constE + ((size_t)2 << 16);

    v4f acc2[2];
    #pragma unroll
    for (int j = 0; j < 2; j++) { acc2[j][0]=0.f; acc2[j][1]=0.f; acc2[j][2]=0.f; acc2[j][3]=0.f; }

    {
        v8h ax = *(const v8h*)(AXt + ((size_t)(b << 10) + n0 + rw * 16 + l15) * 32 + quad * 8);
        #pragma unroll
        for (int j = 0; j < 2; j++) {
            v8h bf = *(const v8h*)(Wxc + (size_t)(ch * 2 + j) * 512 + lu);
            acc2[j] = __builtin_amdgcn_mfma_f32_16x16x32_f16(ax, bf, acc2[j], 0, 0, 0);
        }
    }
    #pragma unroll
    for (int ks = 0; ks < 8; ks++) {
        v8h a = *(const v8h*)&Yt[(rw * 16 + l15) * 264 + ks * 32 + quad * 8];
        #pragma unroll
        for (int j = 0; j < 2; j++) {
            v8h bf = *(const v8h*)(WfcH + (size_t)((ch * 2 + j) * 8 + ks) * 512 + lu);
            acc2[j] = __builtin_amdgcn_mfma_f32_16x16x32_f16(a, bf, acc2[j], 0, 0, 0);
        }
    }

    unsigned short* sT = &S[1][0];   // [64][72]
    #pragma unroll
    for (int j = 0; j < 2; j++) {
        int c = (ch * 2 + j) * 16 + l15;
        float bb = b_c[c];
        #pragma unroll
        for (int rr = 0; rr < 4; rr++) {
            int nl = rw * 16 + quad * 4 + rr;
            size_t row = (size_t)(b << 10) + n0 + nl;
            float pre = acc2[j][rr] + bb + cE[(size_t)(n0 + nl) * 64 + c];
            float cv = tanhf(pre);
            float u = ubuf[row * 64 + c];
            float hv = h[row * 64 + c];
            float hn = u * hv + (1.f - u) * cv;
            h[row * 64 + c] = hn;
            sT[c * 72 + nl] = f2h(hn);
        }
    }
    __syncthreads();
    {
        int c = tid >> 3, n8 = (tid & 7) * 8;
        *(uint4*)(XhH + ((size_t)b * 64 + c) * NN + n0 + n8) = *(uint4*)&sT[c * 72 + n8];
    }
}

// ---------------- h-hop (readout): 128x128 (b-pair) tile, XCD-grouped 1D grid ----------------
__global__ __launch_bounds__(512) void k_hopA(
        const unsigned short* __restrict__ Mf,
        const unsigned short* __restrict__ Xb,
        unsigned short* __restrict__ Yout, int out_stride, int out_gmul, int out_off) {
    int bid = blockIdx.x;
    int rt = bid & 31;
    int bp = bid >> 5;
    int g = rt >> 3;
    int n0 = (rt & 7) * 128;

    __shared__ unsigned short sA[2][16 * 512];
    __shared__ unsigned short sX[2][16 * 512];

    int tid = threadIdx.x;
    int lane = tid & 63, wave = tid >> 6;
    int rh = wave >> 2, cq = wave & 3;
    int l15 = lane & 15, quad = lane >> 4;

    const unsigned short* Xbase = Xb + (size_t)(bp * 2) * 64 * NN;

    v4f acc[4][2];
    #pragma unroll
    for (int i = 0; i < 4; i++)
        #pragma unroll
        for (int j = 0; j < 2; j++) { acc[i][j][0]=0.f; acc[i][j][1]=0.f; acc[i][j][2]=0.f; acc[i][j][3]=0.f; }

    auto STAGE = [&](int buf, int k0) {
        #pragma unroll
        for (int s = 0; s < 4; s++) {
            int id = wave + s * 8;
            if (id < 16) {
                int ah = id >> 3, kh = (id >> 2) & 1, rf = id & 3;
                const unsigned short* src = Mf +
                    ((size_t)(rt * 2 + ah) * 8192 +
                     (size_t)((k0 >> 3) + kh * 4 + quad) * 64 + rf * 16 + l15) * 8;
                gl_lds16(src, &sA[buf][id * 512]);
            } else {
                int xi = id - 16, cj = xi >> 1, kh = xi & 1;
                const unsigned short* src = Xbase +
                    (size_t)(cj * 16 + l15) * NN + k0 + kh * 32 + quad * 8;
                gl_lds16(src, &sX[buf][xi * 512]);
            }
        }
    };

    STAGE(0, 0);
    STAGE(1, 64);

    int lu = lane * 8;
    for (int kt = 0; kt < 16; kt++) {
        int cur = kt & 1;
        if (kt < 15) asm volatile("s_waitcnt vmcnt(4)" ::: "memory");
        else         asm volatile("s_waitcnt vmcnt(0)" ::: "memory");
        __builtin_amdgcn_s_barrier();
        asm volatile("" ::: "memory");
        #pragma unroll
        for (int kh = 0; kh < 2; kh++) {
            v8h a[4], bx[2];
            #pragma unroll
            for (int rf = 0; rf < 4; rf++)
                a[rf] = *(const v8h*)&sA[cur][(rh * 8 + kh * 4 + rf) * 512 + lu];
            #pragma unroll
            for (int j = 0; j < 2; j++)
                bx[j] = *(const v8h*)&sX[cur][((cq * 2 + j) * 2 + kh) * 512 + lu];
            #pragma unroll
            for (int rf = 0; rf < 4; rf++)
                #pragma unroll
                for (int j = 0; j < 2; j++)
                    acc[rf][j] = __builtin_amdgcn_mfma_f32_16x16x32_f16(a[rf], bx[j], acc[rf][j], 0, 0, 0);
        }
        asm volatile("" ::: "memory");
        __builtin_amdgcn_s_barrier();
        asm volatile("" ::: "memory");
        if (kt < 14) STAGE(cur, (kt + 2) * 64);
    }

    #pragma unroll
    for (int rf = 0; rf < 4; rf++)
        #pragma unroll
        for (int j = 0; j < 2; j++) {
            int colloc = cq * 32 + j * 16 + l15;       // 0..127
            int b = bp * 2 + (colloc >> 6);
            int c = colloc & 63;
            unsigned short* Y = Yout + (size_t)b * NN * out_stride + out_gmul * g + out_off + c;
            int rbase = n0 + rh * 64 + rf * 16 + quad * 4;
            #pragma unroll
            for (int rr = 0; rr < 4; rr++)
                Y[(size_t)(rbase + rr) * out_stride] = f2h(acc[rf][j][rr]);
        }
}

// ---------------- out = featd @ (W_diff@W_dec) + bzd, scattered to [b][t][n][f] ----------------
__global__ __launch_bounds__(256) void k_out(
        const unsigned short* __restrict__ featd,
        const unsigned short* __restrict__ Wf_o, const float* __restrict__ bzd,
        float* __restrict__ out) {
    int row0 = blockIdx.x * 64;
    int tid = threadIdx.x, lane = tid & 63, wave = tid >> 6;
    int l15 = lane & 15, quad = lane >> 4;

    v4f acc[6];
    #pragma unroll
    for (int cj = 0; cj < 6; cj++) { acc[cj][0]=0.f; acc[cj][1]=0.f; acc[cj][2]=0.f; acc[cj][3]=0.f; }

    const unsigned short* fbase = featd + (size_t)(row0 + wave * 16 + l15) * DIN + quad * 8;
    #pragma unroll 2
    for (int ks = 0; ks < 10; ks++) {
        v8h a = *(const v8h*)(fbase + ks * 32);
        #pragma unroll
        for (int cj = 0; cj < 6; cj++) {
            v8h bf = *(const v8h*)(Wf_o + (size_t)(cj * 10 + ks) * 512 + lane * 8);
            acc[cj] = __builtin_amdgcn_mfma_f32_16x16x32_f16(a, bf, acc[cj], 0, 0, 0);
        }
    }
    #pragma unroll
    for (int cj = 0; cj < 6; cj++) {
        int o = cj * 16 + l15;
        int t = o >> 3, f = o & 7;
        float bb = bzd[o];
        #pragma unroll
        for (int rr = 0; rr < 4; rr++) {
            int row = row0 + wave * 16 + quad * 4 + rr;
            int b = row >> 10, n = row & 1023;
            out[(((size_t)b * TT + t) * NN + n) * FF + f] = acc[cj][rr] + bb;
        }
    }
}

// ---------------- DiffConv operator build ----------------
__global__ void k_deg(const int* __restrict__ ei32, const float* __restrict__ ew,
                      float* __restrict__ degd, float* __restrict__ degs) {
    int e = blockIdx.x * 256 + threadIdx.x;
    float w = ew[e];
    atomicAdd(&degd[ei32[EE + e]], w);
    atomicAdd(&degs[ei32[e]], w);
}
__global__ void k_spadd(const int* __restrict__ ei32, const float* __restrict__ ew,
                        const float* __restrict__ degd, const float* __restrict__ degs,
                        float* __restrict__ temp) {
    int e = blockIdx.x * 256 + threadIdx.x;
    int s = ei32[e], d = ei32[EE + e];
    float w = ew[e];
    float dd = degd[d], ds = degs[s];
    float wfv = dd > 0.f ? w / dd : 0.f;
    float wbv = ds > 0.f ? w / ds : 0.f;
    atomicAdd(&temp[(size_t)d * NN + s], wfv);
    atomicAdd(&temp[(size_t)NN * NN + (size_t)s * NN + d], wbv);
}
__global__ void k_spconv(const float* __restrict__ temp, unsigned short* __restrict__ Mp) {
    size_t i0 = ((size_t)blockIdx.x * 256 + threadIdx.x) * 8;
    size_t dst = (i0 < (size_t)NN * NN) ? i0 : i0 + (size_t)NN * NN;
    unsigned short h8[8];
    #pragma unroll
    for (int j = 0; j < 8; j++) h8[j] = f2h(temp[i0 + j]);
    *(uint4*)(Mp + dst) = *(uint4*)h8;
}

__global__ void k_featd_h(const float* __restrict__ h, unsigned short* __restrict__ featd) {
    size_t idx = (size_t)blockIdx.x * 256 + threadIdx.x;
    size_t row = idx >> 6; int c = (int)(idx & 63);
    featd[row * DIN + c] = f2h(h[idx]);
}

extern "C" void kernel_launch(void* const* d_in, const int* in_sizes, int n_in,
                              void* d_out, int out_size, void* d_ws, size_t ws_size,
                              hipStream_t stream) {
    const float* x      = (const float*)d_in[0];
    const int*   eiraw  = (const int*)  d_in[1];
    const float* ew     = (const float*)d_in[2];
    const float* adj    = (const float*)d_in[3];
    const float* W_enc  = (const float*)d_in[4];
    const float* b_enc  = (const float*)d_in[5];
    const float* emb    = (const float*)d_in[6];
    const float* W_r    = (const float*)d_in[7];
    const float* b_r    = (const float*)d_in[8];
    const float* W_u    = (const float*)d_in[9];
    const float* b_u    = (const float*)d_in[10];
    const float* W_c    = (const float*)d_in[11];
    const float* b_c    = (const float*)d_in[12];
    const float* W_diff = (const float*)d_in[13];
    const float* b_diff = (const float*)d_in[14];
    const float* W_dec  = (const float*)d_in[15];
    const float* b_dec  = (const float*)d_in[16];

    // ---- workspace ~56 MiB ----
    unsigned short* Mf    = (unsigned short*)d_ws;            // 8 MiB
    unsigned short* XhH   = Mf + (size_t)4096 * NN;           // 2 MiB  h fp16 [b][64][n]
    unsigned short* XhR   = XhH + (size_t)BB * 64 * NN;       // 2 MiB  rh fp16
    unsigned short* featd = XhR + (size_t)BB * 64 * NN;       // 10 MiB [16384][320]
    float* h    = (float*)(featd + (size_t)BB * NN * DIN);    // 4 MiB
    float* ubuf = h + (size_t)BB * NN * HH;                   // 4 MiB
    unsigned short* AXall = (unsigned short*)(ubuf + (size_t)BB * NN * HH); // 12 MiB [tb][n][32]
    unsigned short* Mp    = AXall;                            // 8 MiB overlay (prep & readout)
    unsigned short* XallT = AXall + (size_t)192 * NN * 32;    // 3.125 MiB [1600][1024]
    unsigned short* Eg    = XallT + (size_t)1600 * NN;        // 0.5 MiB [4][1024][64]
    float* sptmp  = (float*)(Eg + (size_t)4 * NN * 64);       // 8 MiB
    float* constE = sptmp + (size_t)2 * NN * NN;              // 768 KiB [3][1024][64]
    float* Veg    = constE + (size_t)3 * NN * 64;             // 24 KiB [3][32][64]
    unsigned short* WfH  = (unsigned short*)(Veg + 3 * 32 * 64); // 3*16384 shorts
    unsigned short* WfrH = WfH;
    unsigned short* WfuH = WfH + 16384;
    unsigned short* WfcH = WfH + 32768;
    unsigned short* Wx   = WfH + 49152;                       // 3*2048 shorts
    unsigned short* Wf_o = Wx + 6144;                         // 30720 shorts
    float* bzd  = (float*)(Wf_o + 30720);
    float* rinv = bzd + ODIM;
    float* cinv = rinv + NN;
    int*   eifl = (int*)(cinv + NN);
    int*   ei32 = eifl + 4;
    float* degd = (float*)(ei32 + 2 * EE);
    float* degs = degd + NN;

    hipMemsetAsync(h, 0, (size_t)BB * NN * HH * 4, stream);
    hipMemsetAsync(XhH, 0, (size_t)BB * 64 * NN * 2, stream);   // h = 0 at t=0

    // ---- build plain M = [Af; Af^2; Ab; Ab^2] (fp16), convert to fragment-major ----
    k_rowsum<<<NN, 256, 0, stream>>>(adj, rinv);
    k_colsum<<<NN / 256, 256, 0, stream>>>(adj, cinv);
    k_prepA<<<dim3(16, 16), 256, 0, stream>>>(adj, rinv, cinv, Mp);
    k_msq<<<dim3(16, 16, 2), 256, 0, stream>>>(Mp);
    k_m2frag<<<2048, 256, 0, stream>>>(Mp, Mf);

    // ---- x/emb transposes, batched x-hop (overwrites Mp region), const folds ----
    k_xT<<<TT * BB, 256, 0, stream>>>(x, XallT);
    k_embT<<<64, 256, 0, stream>>>(emb, XallT);
    k_hopX<<<13 * 32, 512, 0, stream>>>(Mf, XallT, AXall, Eg);
    k_veg<<<24, 256, 0, stream>>>(W_enc, W_r, W_u, W_c, Veg);
    k_constE<<<dim3(256, 3), 256, 0, stream>>>(Eg, b_enc, W_r, W_u, W_c, constE);
    k_wfragH<<<192, 256, 0, stream>>>(W_r, W_u, W_c, WfrH, WfuH, WfcH);
    k_wfragX<<<24, 256, 0, stream>>>(Veg, Wx);
    k_wfragO<<<120, 256, 0, stream>>>(W_diff, W_dec, Wf_o);
    k_bzd<<<1, ODIM, 0, stream>>>(b_diff, W_dec, b_dec, bzd);

    for (int t = 0; t < TT; t++) {
        const unsigned short* AXt = AXall + (size_t)t * BB * NN * 32;
        // fused: 4 ops @ h + fold -> r,u; rh -> XhR, u -> ubuf
        k_hopRU<<<256, 512, 0, stream>>>(Mf, XhH, AXt, WfrH, WfuH, Wx, Wx + 2048,
                                         b_r, b_u, constE, h, XhR, ubuf);
        // fused: 4 ops @ rh + fold -> c; h update -> h, XhH
        k_hopC<<<256, 512, 0, stream>>>(Mf, XhR, AXt, WfcH, Wx + 4096,
                                        b_c, constE, ubuf, h, XhH);
    }

    // ---- DiffConv readout ----
    k_ei_detect<<<1, 256, 0, stream>>>(eiraw, eifl);
    k_ei_norm<<<2 * EE / 256, 256, 0, stream>>>(eiraw, eifl, ei32);
    hipMemsetAsync(degd, 0, (size_t)2 * NN * 4, stream);
    hipMemsetAsync(sptmp, 0, (size_t)2 * NN * NN * 4, stream);
    k_deg<<<EE / 256, 256, 0, stream>>>(ei32, ew, degd, degs);
    k_spadd<<<EE / 256, 256, 0, stream>>>(ei32, ew, degd, degs, sptmp);
    k_spconv<<<2 * NN * NN / (256 * 8), 256, 0, stream>>>(sptmp, Mp);
    k_msq<<<dim3(16, 16, 2), 256, 0, stream>>>(Mp);
    k_m2frag<<<2048, 256, 0, stream>>>(Mp, Mf);
    k_featd_h<<<BB * NN * HH / 256, 256, 0, stream>>>(h, featd);
    // [Sf;Sf2;Sb;Sb2] @ h (fp16 in XhH) -> featd cols 64 + g*64
    k_hopA<<<8 * 32, 512, 0, stream>>>(Mf, XhH, featd, DIN, 64, 64);
    k_out<<<BB * NN / 64, 256, 0, stream>>>(featd, Wf_o, bzd, (float*)d_out);
}

// Round 9
// 722.109 us; speedup vs baseline: 1.5567x; 1.0006x over previous
//
#include <hip/hip_runtime.h>
#include <math.h>

#define BB 16
#define TT 12
#define NN 1024
#define FF 8
#define HH 64
#define EE 32768
#define DIN 320   // H * (2K+1)
#define ODIM 96   // F * HORIZON
#define APAD 40   // k_msq LDS row stride

typedef _Float16 v8h __attribute__((ext_vector_type(8)));
typedef float v4f __attribute__((ext_vector_type(4)));

__device__ __forceinline__ unsigned short f2h(float v) {
    _Float16 h = (_Float16)v;          // RNE v_cvt_f16_f32
    unsigned short u;
    __builtin_memcpy(&u, &h, 2);
    return u;
}
__device__ __forceinline__ float h2f(unsigned short u) {
    _Float16 h;
    __builtin_memcpy(&h, &u, 2);
    return (float)h;
}
// async global->LDS, 16B per lane; LDS dst = wave-uniform base + lane*16
__device__ __forceinline__ void gl_lds16(const void* g, void* l) {
    __builtin_amdgcn_global_load_lds(
        (const __attribute__((address_space(1))) unsigned int*)g,
        (__attribute__((address_space(3))) unsigned int*)l, 16, 0, 0);
}

// ---------------- edge_index insurance ----------------
__global__ void k_ei_detect(const int* __restrict__ ei_raw, int* __restrict__ flag) {
    __shared__ int s[256];
    s[threadIdx.x] = ei_raw[2 * threadIdx.x + 1];
    __syncthreads();
    for (int st = 128; st > 0; st >>= 1) {
        if (threadIdx.x < st) s[threadIdx.x] |= s[threadIdx.x + st];
        __syncthreads();
    }
    if (threadIdx.x == 0) flag[0] = (s[0] == 0) ? 1 : 0;
}
__global__ void k_ei_norm(const int* __restrict__ ei_raw, const int* __restrict__ flag,
                          int* __restrict__ ei32) {
    int j = blockIdx.x * 256 + threadIdx.x;
    ei32[j] = flag[0] ? ei_raw[2 * j] : ei_raw[j];
}

// ---------------- support normalization ----------------
__global__ void k_rowsum(const float* __restrict__ adj, float* __restrict__ rinv) {
    __shared__ float s[256];
    int i = blockIdx.x;
    float acc = 0.f;
    for (int j = threadIdx.x; j < NN; j += 256) acc += adj[i * NN + j];
    s[threadIdx.x] = acc;
    __syncthreads();
    for (int st = 128; st > 0; st >>= 1) {
        if (threadIdx.x < st) s[threadIdx.x] += s[threadIdx.x + st];
        __syncthreads();
    }
    if (threadIdx.x == 0) rinv[i] = (s[0] != 0.f) ? 1.f / s[0] : 0.f;
}
// parallel column sums: 64 blocks x 16 rows, atomic partials
__global__ void k_colsumP(const float* __restrict__ adj, float* __restrict__ csum) {
    int bi = blockIdx.x;
    int j4 = threadIdx.x * 4;
    float4 acc = {0.f, 0.f, 0.f, 0.f};
    const float* base = adj + (size_t)bi * 16 * NN + j4;
    #pragma unroll
    for (int r = 0; r < 16; r++) {
        float4 v = *(const float4*)(base + (size_t)r * NN);
        acc.x += v.x; acc.y += v.y; acc.z += v.z; acc.w += v.w;
    }
    atomicAdd(&csum[j4 + 0], acc.x);
    atomicAdd(&csum[j4 + 1], acc.y);
    atomicAdd(&csum[j4 + 2], acc.z);
    atomicAdd(&csum[j4 + 3], acc.w);
}
__global__ void k_cinv(const float* __restrict__ csum, float* __restrict__ cinv) {
    int j = blockIdx.x * 256 + threadIdx.x;
    float s = csum[j];
    cinv[j] = (s != 0.f) ? 1.f / s : 0.f;
}

// ---------------- Af -> plain rows 0..1023, Ab -> plain rows 2048..3071 (single fp16) ----------------
__global__ __launch_bounds__(256) void k_prepA(
        const float* __restrict__ adj, const float* __restrict__ rinv,
        const float* __restrict__ cinv, unsigned short* __restrict__ Mp) {
    int w0 = blockIdx.x * 64, v0 = blockIdx.y * 64;
    __shared__ float T[64][68];
    int row = threadIdx.x >> 2, cs = (threadIdx.x & 3) * 16;
    #pragma unroll
    for (int j = 0; j < 4; j++)
        *(float4*)&T[row][cs + j * 4] = *(const float4*)(adj + (size_t)(w0 + row) * NN + v0 + cs + j * 4);
    __syncthreads();
    {
        float sc = rinv[w0 + row];
        unsigned short h8[16];
        #pragma unroll
        for (int j = 0; j < 16; j++) h8[j] = f2h(T[row][cs + j] * sc);
        size_t ofs = (size_t)(w0 + row) * NN + v0 + cs;
        ((uint4*)(Mp + ofs))[0] = *(uint4*)&h8[0];
        ((uint4*)(Mp + ofs))[1] = *(uint4*)&h8[8];
    }
    {
        float sc = cinv[v0 + row];
        unsigned short h8[16];
        #pragma unroll
        for (int j = 0; j < 16; j++) h8[j] = f2h(T[cs + j][row] * sc);
        size_t ofs = (size_t)2048 * NN + (size_t)(v0 + row) * NN + w0 + cs;
        ((uint4*)(Mp + ofs))[0] = *(uint4*)&h8[0];
        ((uint4*)(Mp + ofs))[1] = *(uint4*)&h8[8];
    }
}

// ---------------- plain M rows (zz) squared: rows zz*2048 -> zz*2048+1024 ----------------
__global__ __launch_bounds__(256) void k_msq(unsigned short* __restrict__ M) {
    int zz = blockIdx.z;
    size_t srcb = (size_t)zz * 2048 * NN;
    size_t dstb = srcb + (size_t)1024 * NN;
    int w0 = blockIdx.x * 64, n0 = blockIdx.y * 64;

    __shared__ unsigned short sA[64 * APAD];
    __shared__ unsigned short sB[64 * APAD];

    int tid = threadIdx.x;
    int lane = tid & 63, wave = tid >> 6;
    int wr = (wave >> 1) * 32, wc = (wave & 1) * 32;
    int l15 = lane & 15, quad = lane >> 4;
    int arow = tid >> 2, akk = (tid & 3) * 8;
    int bkr = tid & 31, bc8 = (tid >> 5) * 8;

    v4f acc[2][2];
    #pragma unroll
    for (int i = 0; i < 2; i++)
        #pragma unroll
        for (int j = 0; j < 2; j++) { acc[i][j][0]=0.f; acc[i][j][1]=0.f; acc[i][j][2]=0.f; acc[i][j][3]=0.f; }

    for (int k0 = 0; k0 < NN; k0 += 32) {
        *(uint4*)&sA[arow * APAD + akk] = *(const uint4*)(M + srcb + (size_t)(w0 + arow) * NN + k0 + akk);
        uint4 bh = *(const uint4*)(M + srcb + (size_t)(k0 + bkr) * NN + n0 + bc8);
        const unsigned short* ph = (const unsigned short*)&bh;
        #pragma unroll
        for (int j = 0; j < 8; j++) sB[(bc8 + j) * APAD + bkr] = ph[j];
        __syncthreads();

        v8h a0 = *(const v8h*)&sA[(wr + l15) * APAD + quad * 8];
        v8h a1 = *(const v8h*)&sA[(wr + 16 + l15) * APAD + quad * 8];
        #pragma unroll
        for (int j = 0; j < 2; j++) {
            v8h bb = *(const v8h*)&sB[(wc + j * 16 + l15) * APAD + quad * 8];
            acc[0][j] = __builtin_amdgcn_mfma_f32_16x16x32_f16(a0, bb, acc[0][j], 0, 0, 0);
            acc[1][j] = __builtin_amdgcn_mfma_f32_16x16x32_f16(a1, bb, acc[1][j], 0, 0, 0);
        }
        __syncthreads();
    }

    #pragma unroll
    for (int i = 0; i < 2; i++)
        #pragma unroll
        for (int j = 0; j < 2; j++) {
            int rb = w0 + wr + i * 16 + quad * 4;
            int cc = n0 + wc + j * 16 + l15;
            #pragma unroll
            for (int rr = 0; rr < 4; rr++)
                M[dstb + (size_t)(rb + rr) * NN + cc] = f2h(acc[i][j][rr]);
        }
}

// ---------------- plain -> fragment-major: chunk t = (T*128 + kc)*64 + rowloc ----------------
__global__ void k_m2frag(const unsigned short* __restrict__ P, unsigned short* __restrict__ F) {
    size_t t = (size_t)blockIdx.x * 256 + threadIdx.x;
    int rowloc = (int)(t & 63);
    int kc = (int)((t >> 6) & 127);
    int T = (int)(t >> 13);
    size_t src = ((size_t)(T * 64 + rowloc) * NN) + kc * 8;
    *(uint4*)(F + t * 8) = *(const uint4*)(P + src);
}

// ---------------- x -> XallT rows: XallT[(t*16+b)*8+f][n] fp16 ----------------
__global__ void k_xT(const float* __restrict__ x, unsigned short* __restrict__ XallT) {
    int bx = blockIdx.x;            // t*16+b
    int t = bx >> 4, b = bx & 15;
    int tid = threadIdx.x;
    int f = tid & 7, half = tid >> 3;   // half 0..31
    const float* xs = x + ((size_t)b * TT + t) * NN * FF + f;
    int n0 = half * 32;
    unsigned short v[32];
    #pragma unroll
    for (int i = 0; i < 32; i++) v[i] = f2h(xs[(size_t)(n0 + i) * FF]);
    unsigned short* dst = XallT + ((size_t)bx * 8 + f) * NN + n0;
    #pragma unroll
    for (int i = 0; i < 4; i++) *(uint4*)(dst + i * 8) = *(uint4*)&v[i * 8];
}
// ---------------- emb -> XallT rows 1536..1599: embT[c][n] ----------------
__global__ void k_embT(const float* __restrict__ emb, unsigned short* __restrict__ XallT) {
    int c = blockIdx.x;
    int n0 = threadIdx.x * 4;
    unsigned short v[4];
    #pragma unroll
    for (int j = 0; j < 4; j++) v[j] = f2h(emb[(size_t)(n0 + j) * HH + c]);
    *(uint2*)(XallT + (size_t)(1536 + c) * NN + n0) = *(uint2*)v;
}

// ---------------- batched x-hop: 128x128 tile, XCD-grouped 1D grid (bid = y*32 + rt) ------------
__global__ __launch_bounds__(512) void k_hopX(
        const unsigned short* __restrict__ Mf,
        const unsigned short* __restrict__ XallT,
        unsigned short* __restrict__ AX, unsigned short* __restrict__ Eg) {
    int bid = blockIdx.x;
    int rt = bid & 31;          // XCD = bid%8 = rt%8
    int y  = bid >> 5;
    int g = rt >> 3;
    int n0 = (rt & 7) * 128;
    int c0 = y * 128;

    __shared__ unsigned short sA[2][16 * 512];
    __shared__ unsigned short sX[2][16 * 512];

    int tid = threadIdx.x;
    int lane = tid & 63, wave = tid >> 6;   // 8 waves
    int rh = wave >> 2, cq = wave & 3;
    int l15 = lane & 15, quad = lane >> 4;

    v4f acc[4][2];
    #pragma unroll
    for (int i = 0; i < 4; i++)
        #pragma unroll
        for (int j = 0; j < 2; j++) { acc[i][j][0]=0.f; acc[i][j][1]=0.f; acc[i][j][2]=0.f; acc[i][j][3]=0.f; }

    auto STAGE = [&](int buf, int k0) {
        #pragma unroll
        for (int s = 0; s < 4; s++) {
            int id = wave + s * 8;
            if (id < 16) {
                int ah = id >> 3, kh = (id >> 2) & 1, rf = id & 3;
                const unsigned short* src = Mf +
                    ((size_t)(rt * 2 + ah) * 8192 +
                     (size_t)((k0 >> 3) + kh * 4 + quad) * 64 + rf * 16 + l15) * 8;
                gl_lds16(src, &sA[buf][id * 512]);
            } else {
                int xi = id - 16, cj = xi >> 1, kh = xi & 1;
                const unsigned short* src = XallT +
                    (size_t)(c0 + cj * 16 + l15) * NN + k0 + kh * 32 + quad * 8;
                gl_lds16(src, &sX[buf][xi * 512]);
            }
        }
    };

    STAGE(0, 0);
    STAGE(1, 64);

    int lu = lane * 8;
    for (int kt = 0; kt < 16; kt++) {
        int cur = kt & 1;
        if (kt < 15) asm volatile("s_waitcnt vmcnt(4)" ::: "memory");
        else         asm volatile("s_waitcnt vmcnt(0)" ::: "memory");
        __builtin_amdgcn_s_barrier();
        asm volatile("" ::: "memory");
        #pragma unroll
        for (int kh = 0; kh < 2; kh++) {
            v8h a[4], bx[2];
            #pragma unroll
            for (int rf = 0; rf < 4; rf++)
                a[rf] = *(const v8h*)&sA[cur][(rh * 8 + kh * 4 + rf) * 512 + lu];
            #pragma unroll
            for (int j = 0; j < 2; j++)
                bx[j] = *(const v8h*)&sX[cur][((cq * 2 + j) * 2 + kh) * 512 + lu];
            #pragma unroll
            for (int rf = 0; rf < 4; rf++)
                #pragma unroll
                for (int j = 0; j < 2; j++)
                    acc[rf][j] = __builtin_amdgcn_mfma_f32_16x16x32_f16(a[rf], bx[j], acc[rf][j], 0, 0, 0);
        }
        asm volatile("" ::: "memory");
        __builtin_amdgcn_s_barrier();
        asm volatile("" ::: "memory");
        if (kt < 14) STAGE(cur, (kt + 2) * 64);
    }

    #pragma unroll
    for (int rf = 0; rf < 4; rf++)
        #pragma unroll
        for (int j = 0; j < 2; j++) {
            int col = c0 + cq * 32 + j * 16 + l15;
            #pragma unroll
            for (int rr = 0; rr < 4; rr++) {
                int nrow = n0 + rh * 64 + rf * 16 + quad * 4 + rr;
                if (col < 1536) {
                    int tb = col >> 3, f = col & 7;
                    AX[((size_t)tb * NN + nrow) * 32 + g * 8 + f] = f2h(acc[rf][j][rr]);
                } else if (col < 1600) {
                    int cc = col - 1536;
                    Eg[((size_t)(g << 10) + nrow) * 64 + cc] = f2h(acc[rf][j][rr]);
                }
            }
        }
}

// ---------------- Veg[G][g*8+f][c] = W_enc @ W_G(x-block g) ----------------
__global__ void k_veg(const float* __restrict__ W_enc,
                      const float* __restrict__ W_r, const float* __restrict__ W_u,
                      const float* __restrict__ W_c, float* __restrict__ Veg) {
    int idx = blockIdx.x * 256 + threadIdx.x;    // 3*32*64
    int c = idx & 63;
    int gf = (idx >> 6) & 31;
    int G = idx >> 11;
    int g = gf >> 3, f = gf & 7;
    const float* W = (G == 0) ? W_r : ((G == 1) ? W_u : W_c);
    float acc = 0.f;
    for (int c2 = 0; c2 < 64; c2++)
        acc += W_enc[f * HH + c2] * W[(size_t)(g * 128 + c2) * HH + c];
    Veg[idx] = acc;
}

// ---------------- constE[G][n][c] = sum_g (Eg[g][n] + b_enc) @ W_G(x-block g) ----------------
__global__ void k_constE(const unsigned short* __restrict__ Eg, const float* __restrict__ b_enc,
                         const float* __restrict__ W_r, const float* __restrict__ W_u,
                         const float* __restrict__ W_c, float* __restrict__ constE) {
    int G = blockIdx.y;
    int n = blockIdx.x * 4 + (threadIdx.x >> 6);
    int c = threadIdx.x & 63;
    const float* W = (G == 0) ? W_r : ((G == 1) ? W_u : W_c);
    float acc = 0.f;
    for (int g = 0; g < 4; g++)
        for (int c2 = 0; c2 < 64; c2++)
            acc += (h2f(Eg[((size_t)(g << 10) + n) * 64 + c2]) + b_enc[c2]) *
                   W[(size_t)(g * 128 + c2) * HH + c];
    constE[((size_t)G << 16) + (size_t)n * 64 + c] = acc;
}

// ---------------- W h-block -> fold fragments: [G][cj*8+ks][512] ----------------
__global__ void k_wfragH(const float* __restrict__ W_r, const float* __restrict__ W_u,
                         const float* __restrict__ W_c,
                         unsigned short* __restrict__ Fr, unsigned short* __restrict__ Fu,
                         unsigned short* __restrict__ Fc) {
    int idx = blockIdx.x * 256 + threadIdx.x;   // 3 * 16384
    int G = idx >> 14;
    int r = idx & 16383;
    int e = r & 7, l = (r >> 3) & 63;
    int rest = r >> 9;                          // cj*8 + ks
    int ks = rest & 7, cj = rest >> 3;
    int c = cj * 16 + (l & 15);
    int k = ks * 32 + (l >> 4) * 8 + e;
    int g = k >> 6, c2 = k & 63;
    const float* W = (G == 0) ? W_r : ((G == 1) ? W_u : W_c);
    unsigned short* F = (G == 0) ? Fr : ((G == 1) ? Fu : Fc);
    F[r] = f2h(W[(size_t)(g * 128 + 64 + c2) * HH + c]);
}
// ---------------- Veg -> x-fold fragments: [G][cj][512] ----------------
__global__ void k_wfragX(const float* __restrict__ Veg, unsigned short* __restrict__ Wx) {
    int idx = blockIdx.x * 256 + threadIdx.x;   // 3 * 2048
    int G = idx >> 11;
    int r = idx & 2047;
    int e = r & 7, l = (r >> 3) & 63;
    int cj = r >> 9;
    int c = cj * 16 + (l & 15);
    int k = (l >> 4) * 8 + e;
    Wx[idx] = f2h(Veg[(size_t)G * 2048 + (size_t)k * 64 + c]);
}

// ---------------- fused output W: Wf_o frag of (W_diff @ W_dec), 6 cj x 10 ks ----------------
__global__ void k_wfragO(const float* __restrict__ W_diff, const float* __restrict__ W_dec,
                         unsigned short* __restrict__ Wf) {
    int idx = blockIdx.x * 256 + threadIdx.x;   // 6*10*512 = 30720
    int e = idx & 7, l = (idx >> 3) & 63;
    int rest = idx >> 9;
    int ks = rest % 10, cj = rest / 10;
    int o = cj * 16 + (l & 15);
    int k = ks * 32 + (l >> 4) * 8 + e;
    float acc = 0.f;
    for (int c = 0; c < 64; c++) acc += W_diff[(size_t)k * HH + c] * W_dec[(size_t)c * ODIM + o];
    Wf[idx] = f2h(acc);
}
__global__ void k_bzd(const float* __restrict__ b_diff, const float* __restrict__ W_dec,
                      const float* __restrict__ b_dec, float* __restrict__ bzd) {
    int o = threadIdx.x;  // 96
    float acc = b_dec[o];
    for (int c = 0; c < 64; c++) acc += b_diff[c] * W_dec[(size_t)c * ODIM + o];
    bzd[o] = acc;
}

// ================= fused hop+gates: 32 rows x 4 ops x 1 batch, fold -> r,u =================
// grid 512: bid = b*32 + nth; XCD = nth%8 (A slice 1 MB/XCD, Xh 2 MB/XCD -> L2-fit)
__global__ __launch_bounds__(512) void k_hopRU(
        const unsigned short* __restrict__ Mf,
        const unsigned short* __restrict__ XhH,   // h fp16 [b][64][n]
        const unsigned short* __restrict__ AXt,   // [b][1024][32]
        const unsigned short* __restrict__ WfrH, const unsigned short* __restrict__ WfuH,
        const unsigned short* __restrict__ Wxr, const unsigned short* __restrict__ Wxu,
        const float* __restrict__ b_r, const float* __restrict__ b_u,
        const float* __restrict__ constE,
        const float* __restrict__ h,
        unsigned short* __restrict__ XhR, float* __restrict__ ubuf) {
    int bid = blockIdx.x;
    int b = bid >> 5, nth = bid & 31;
    int nt = nth >> 1, hb = nth & 1;
    int n0 = nth * 32;

    __shared__ unsigned short S[2][24 * 512];   // 48 KiB

    int tid = threadIdx.x;
    int lane = tid & 63, wave = tid >> 6;
    int l15 = lane & 15, quad = lane >> 4;
    int g = wave >> 1, rh = wave & 1;

    const unsigned short* Xbase = XhH + (size_t)b * 64 * NN;

    v4f acc[4];
    #pragma unroll
    for (int j = 0; j < 4; j++) { acc[j][0]=0.f; acc[j][1]=0.f; acc[j][2]=0.f; acc[j][3]=0.f; }

    auto STAGE = [&](int buf, int k0) {
        #pragma unroll
        for (int s = 0; s < 3; s++) {
            int id = wave + s * 8;
            if (id < 16) {
                int gg = id >> 2, kh = (id >> 1) & 1, rfi = id & 1;
                int rf = hb * 2 + rfi;
                const unsigned short* src = Mf +
                    ((size_t)(gg * 16 + nt) * 8192 +
                     (size_t)((k0 >> 3) + kh * 4 + quad) * 64 + rf * 16 + l15) * 8;
                gl_lds16(src, &S[buf][id * 512]);
            } else {
                int xi = id - 16, cj = xi >> 1, kh = xi & 1;
                const unsigned short* src = Xbase +
                    (size_t)(cj * 16 + l15) * NN + k0 + kh * 32 + quad * 8;
                gl_lds16(src, &S[buf][id * 512]);
            }
        }
    };

    STAGE(0, 0);
    STAGE(1, 64);

    int lu = lane * 8;
    for (int kt = 0; kt < 16; kt++) {
        int cur = kt & 1;
        if (kt < 15) asm volatile("s_waitcnt vmcnt(3)" ::: "memory");
        else         asm volatile("s_waitcnt vmcnt(0)" ::: "memory");
        __builtin_amdgcn_s_barrier();
        asm volatile("" ::: "memory");
        #pragma unroll
        for (int kh = 0; kh < 2; kh++) {
            v8h a = *(const v8h*)&S[cur][(g * 4 + kh * 2 + rh) * 512 + lu];
            #pragma unroll
            for (int cj = 0; cj < 4; cj++) {
                v8h bx = *(const v8h*)&S[cur][(16 + cj * 2 + kh) * 512 + lu];
                acc[cj] = __builtin_amdgcn_mfma_f32_16x16x32_f16(a, bx, acc[cj], 0, 0, 0);
            }
        }
        asm volatile("" ::: "memory");
        __builtin_amdgcn_s_barrier();
        asm volatile("" ::: "memory");
        if (kt < 14) STAGE(cur, (kt + 2) * 64);
    }

    // Yt[32][264] fp16 in S[0]
    unsigned short* Yt = &S[0][0];
    #pragma unroll
    for (int cj = 0; cj < 4; cj++) {
        int col = g * 64 + cj * 16 + l15;
        #pragma unroll
        for (int rr = 0; rr < 4; rr++) {
            int row = rh * 16 + quad * 4 + rr;
            Yt[row * 264 + col] = f2h(acc[cj][rr]);
        }
    }
    __syncthreads();

    // fold: waves = gate(2) x rw(2) x ch(2); 16 rows x 32 cols each
    int gate = wave >> 2, rw = (wave >> 1) & 1, ch = wave & 1;
    const unsigned short* WH = gate ? WfuH : WfrH;
    const unsigned short* WX = gate ? Wxu : Wxr;
    const float* bias = gate ? b_u : b_r;
    const float* cE = constE + ((size_t)gate << 16);

    v4f acc2[2];
    #pragma unroll
    for (int j = 0; j < 2; j++) { acc2[j][0]=0.f; acc2[j][1]=0.f; acc2[j][2]=0.f; acc2[j][3]=0.f; }

    {
        v8h ax = *(const v8h*)(AXt + ((size_t)(b << 10) + n0 + rw * 16 + l15) * 32 + quad * 8);
        #pragma unroll
        for (int j = 0; j < 2; j++) {
            v8h bf = *(const v8h*)(WX + (size_t)(ch * 2 + j) * 512 + lu);
            acc2[j] = __builtin_amdgcn_mfma_f32_16x16x32_f16(ax, bf, acc2[j], 0, 0, 0);
        }
    }
    #pragma unroll
    for (int ks = 0; ks < 8; ks++) {
        v8h a = *(const v8h*)&Yt[(rw * 16 + l15) * 264 + ks * 32 + quad * 8];
        #pragma unroll
        for (int j = 0; j < 2; j++) {
            v8h bf = *(const v8h*)(WH + (size_t)((ch * 2 + j) * 8 + ks) * 512 + lu);
            acc2[j] = __builtin_amdgcn_mfma_f32_16x16x32_f16(a, bf, acc2[j], 0, 0, 0);
        }
    }

    unsigned short* sT = &S[1][0];   // [64 c][36]
    if (gate == 0) {
        #pragma unroll
        for (int j = 0; j < 2; j++) {
            int c = (ch * 2 + j) * 16 + l15;
            float bb = bias[c];
            #pragma unroll
            for (int rr = 0; rr < 4; rr++) {
                int nl = rw * 16 + quad * 4 + rr;
                size_t row = (size_t)(b << 10) + n0 + nl;
                float pre = acc2[j][rr] + bb + cE[(size_t)(n0 + nl) * 64 + c];
                float r = 1.f / (1.f + expf(-pre));
                sT[c * 36 + nl] = f2h(r * h[row * 64 + c]);
            }
        }
    } else {
        #pragma unroll
        for (int j = 0; j < 2; j++) {
            int c = (ch * 2 + j) * 16 + l15;
            float bb = bias[c];
            #pragma unroll
            for (int rr = 0; rr < 4; rr++) {
                int nl = rw * 16 + quad * 4 + rr;
                size_t row = (size_t)(b << 10) + n0 + nl;
                float pre = acc2[j][rr] + bb + cE[(size_t)(n0 + nl) * 64 + c];
                ubuf[row * 64 + c] = 1.f / (1.f + expf(-pre));
            }
        }
    }
    __syncthreads();
    {
        int c = tid >> 3, n4 = (tid & 7) * 4;
        *(uint2*)(XhR + ((size_t)b * 64 + c) * NN + n0 + n4) = *(uint2*)&sT[c * 36 + n4];
    }
}

// ================= fused hop+candidate: 32 rows, fold -> c, h update =================
__global__ __launch_bounds__(512) void k_hopC(
        const unsigned short* __restrict__ Mf,
        const unsigned short* __restrict__ XhR,   // rh fp16 [b][64][n]
        const unsigned short* __restrict__ AXt,
        const unsigned short* __restrict__ WfcH, const unsigned short* __restrict__ Wxc,
        const float* __restrict__ b_c,
        const float* __restrict__ constE,
        const float* __restrict__ ubuf,
        float* __restrict__ h, unsigned short* __restrict__ XhH) {
    int bid = blockIdx.x;
    int b = bid >> 5, nth = bid & 31;
    int nt = nth >> 1, hb = nth & 1;
    int n0 = nth * 32;

    __shared__ unsigned short S[2][24 * 512];

    int tid = threadIdx.x;
    int lane = tid & 63, wave = tid >> 6;
    int l15 = lane & 15, quad = lane >> 4;
    int g = wave >> 1, rh = wave & 1;

    const unsigned short* Xbase = XhR + (size_t)b * 64 * NN;

    v4f acc[4];
    #pragma unroll
    for (int j = 0; j < 4; j++) { acc[j][0]=0.f; acc[j][1]=0.f; acc[j][2]=0.f; acc[j][3]=0.f; }

    auto STAGE = [&](int buf, int k0) {
        #pragma unroll
        for (int s = 0; s < 3; s++) {
            int id = wave + s * 8;
            if (id < 16) {
                int gg = id >> 2, kh = (id >> 1) & 1, rfi = id & 1;
                int rf = hb * 2 + rfi;
                const unsigned short* src = Mf +
                    ((size_t)(gg * 16 + nt) * 8192 +
                     (size_t)((k0 >> 3) + kh * 4 + quad) * 64 + rf * 16 + l15) * 8;
                gl_lds16(src, &S[buf][id * 512]);
            } else {
                int xi = id - 16, cj = xi >> 1, kh = xi & 1;
                const unsigned short* src = Xbase +
                    (size_t)(cj * 16 + l15) * NN + k0 + kh * 32 + quad * 8;
                gl_lds16(src, &S[buf][id * 512]);
            }
        }
    };

    STAGE(0, 0);
    STAGE(1, 64);

    int lu = lane * 8;
    for (int kt = 0; kt < 16; kt++) {
        int cur = kt & 1;
        if (kt < 15) asm volatile("s_waitcnt vmcnt(3)" ::: "memory");
        else         asm volatile("s_waitcnt vmcnt(0)" ::: "memory");
        __builtin_amdgcn_s_barrier();
        asm volatile("" ::: "memory");
        #pragma unroll
        for (int kh = 0; kh < 2; kh++) {
            v8h a = *(const v8h*)&S[cur][(g * 4 + kh * 2 + rh) * 512 + lu];
            #pragma unroll
            for (int cj = 0; cj < 4; cj++) {
                v8h bx = *(const v8h*)&S[cur][(16 + cj * 2 + kh) * 512 + lu];
                acc[cj] = __builtin_amdgcn_mfma_f32_16x16x32_f16(a, bx, acc[cj], 0, 0, 0);
            }
        }
        asm volatile("" ::: "memory");
        __builtin_amdgcn_s_barrier();
        asm volatile("" ::: "memory");
        if (kt < 14) STAGE(cur, (kt + 2) * 64);
    }

    unsigned short* Yt = &S[0][0];
    #pragma unroll
    for (int cj = 0; cj < 4; cj++) {
        int col = g * 64 + cj * 16 + l15;
        #pragma unroll
        for (int rr = 0; rr < 4; rr++) {
            int row = rh * 16 + quad * 4 + rr;
            Yt[row * 264 + col] = f2h(acc[cj][rr]);
        }
    }
    __syncthreads();

    // fold: waves = ch(4 col-quarters) x rw(2); 16 rows x 16 cols each
    int ch = wave >> 1, rw = wave & 1;
    const float* cE = constE + ((size_t)2 << 16);

    v4f acc2;
    acc2[0]=0.f; acc2[1]=0.f; acc2[2]=0.f; acc2[3]=0.f;

    {
        v8h ax = *(const v8h*)(AXt + ((size_t)(b << 10) + n0 + rw * 16 + l15) * 32 + quad * 8);
        v8h bf = *(const v8h*)(Wxc + (size_t)ch * 512 + lu);
        acc2 = __builtin_amdgcn_mfma_f32_16x16x32_f16(ax, bf, acc2, 0, 0, 0);
    }
    #pragma unroll
    for (int ks = 0; ks < 8; ks++) {
        v8h a = *(const v8h*)&Yt[(rw * 16 + l15) * 264 + ks * 32 + quad * 8];
        v8h bf = *(const v8h*)(WfcH + (size_t)(ch * 8 + ks) * 512 + lu);
        acc2 = __builtin_amdgcn_mfma_f32_16x16x32_f16(a, bf, acc2, 0, 0, 0);
    }

    unsigned short* sT = &S[1][0];   // [64 c][36]
    {
        int c = ch * 16 + l15;
        float bb = b_c[c];
        #pragma unroll
        for (int rr = 0; rr < 4; rr++) {
            int nl = rw * 16 + quad * 4 + rr;
            size_t row = (size_t)(b << 10) + n0 + nl;
            float pre = acc2[rr] + bb + cE[(size_t)(n0 + nl) * 64 + c];
            float cv = tanhf(pre);
            float u = ubuf[row * 64 + c];
            float hv = h[row * 64 + c];
            float hn = u * hv + (1.f - u) * cv;
            h[row * 64 + c] = hn;
            sT[c * 36 + nl] = f2h(hn);
        }
    }
    __syncthreads();
    {
        int c = tid >> 3, n4 = (tid & 7) * 4;
        *(uint2*)(XhH + ((size_t)b * 64 + c) * NN + n0 + n4) = *(uint2*)&sT[c * 36 + n4];
    }
}

// ---------------- h-hop (readout): 128x128 (b-pair) tile, XCD-grouped 1D grid ----------------
__global__ __launch_bounds__(512) void k_hopA(
        const unsigned short* __restrict__ Mf,
        const unsigned short* __restrict__ Xb,
        unsigned short* __restrict__ Yout, int out_stride, int out_gmul, int out_off) {
    int bid = blockIdx.x;
    int rt = bid & 31;
    int bp = bid >> 5;
    int g = rt >> 3;
    int n0 = (rt & 7) * 128;

    __shared__ unsigned short sA[2][16 * 512];
    __shared__ unsigned short sX[2][16 * 512];

    int tid = threadIdx.x;
    int lane = tid & 63, wave = tid >> 6;
    int rh = wave >> 2, cq = wave & 3;
    int l15 = lane & 15, quad = lane >> 4;

    const unsigned short* Xbase = Xb + (size_t)(bp * 2) * 64 * NN;

    v4f acc[4][2];
    #pragma unroll
    for (int i = 0; i < 4; i++)
        #pragma unroll
        for (int j = 0; j < 2; j++) { acc[i][j][0]=0.f; acc[i][j][1]=0.f; acc[i][j][2]=0.f; acc[i][j][3]=0.f; }

    auto STAGE = [&](int buf, int k0) {
        #pragma unroll
        for (int s = 0; s < 4; s++) {
            int id = wave + s * 8;
            if (id < 16) {
                int ah = id >> 3, kh = (id >> 2) & 1, rf = id & 3;
                const unsigned short* src = Mf +
                    ((size_t)(rt * 2 + ah) * 8192 +
                     (size_t)((k0 >> 3) + kh * 4 + quad) * 64 + rf * 16 + l15) * 8;
                gl_lds16(src, &sA[buf][id * 512]);
            } else {
                int xi = id - 16, cj = xi >> 1, kh = xi & 1;
                const unsigned short* src = Xbase +
                    (size_t)(cj * 16 + l15) * NN + k0 + kh * 32 + quad * 8;
                gl_lds16(src, &sX[buf][xi * 512]);
            }
        }
    };

    STAGE(0, 0);
    STAGE(1, 64);

    int lu = lane * 8;
    for (int kt = 0; kt < 16; kt++) {
        int cur = kt & 1;
        if (kt < 15) asm volatile("s_waitcnt vmcnt(4)" ::: "memory");
        else         asm volatile("s_waitcnt vmcnt(0)" ::: "memory");
        __builtin_amdgcn_s_barrier();
        asm volatile("" ::: "memory");
        #pragma unroll
        for (int kh = 0; kh < 2; kh++) {
            v8h a[4], bx[2];
            #pragma unroll
            for (int rf = 0; rf < 4; rf++)
                a[rf] = *(const v8h*)&sA[cur][(rh * 8 + kh * 4 + rf) * 512 + lu];
            #pragma unroll
            for (int j = 0; j < 2; j++)
                bx[j] = *(const v8h*)&sX[cur][((cq * 2 + j) * 2 + kh) * 512 + lu];
            #pragma unroll
            for (int rf = 0; rf < 4; rf++)
                #pragma unroll
                for (int j = 0; j < 2; j++)
                    acc[rf][j] = __builtin_amdgcn_mfma_f32_16x16x32_f16(a[rf], bx[j], acc[rf][j], 0, 0, 0);
        }
        asm volatile("" ::: "memory");
        __builtin_amdgcn_s_barrier();
        asm volatile("" ::: "memory");
        if (kt < 14) STAGE(cur, (kt + 2) * 64);
    }

    #pragma unroll
    for (int rf = 0; rf < 4; rf++)
        #pragma unroll
        for (int j = 0; j < 2; j++) {
            int colloc = cq * 32 + j * 16 + l15;       // 0..127
            int b = bp * 2 + (colloc >> 6);
            int c = colloc & 63;
            unsigned short* Y = Yout + (size_t)b * NN * out_stride + out_gmul * g + out_off + c;
            int rbase = n0 + rh * 64 + rf * 16 + quad * 4;
            #pragma unroll
            for (int rr = 0; rr < 4; rr++)
                Y[(size_t)(rbase + rr) * out_stride] = f2h(acc[rf][j][rr]);
        }
}

// ---------------- out = featd @ (W_diff@W_dec) + bzd, scattered to [b][t][n][f] ----------------
__global__ __launch_bounds__(256) void k_out(
        const unsigned short* __restrict__ featd,
        const unsigned short* __restrict__ Wf_o, const float* __restrict__ bzd,
        float* __restrict__ out) {
    int row0 = blockIdx.x * 64;
    int tid = threadIdx.x, lane = tid & 63, wave = tid >> 6;
    int l15 = lane & 15, quad = lane >> 4;

    v4f acc[6];
    #pragma unroll
    for (int cj = 0; cj < 6; cj++) { acc[cj][0]=0.f; acc[cj][1]=0.f; acc[cj][2]=0.f; acc[cj][3]=0.f; }

    const unsigned short* fbase = featd + (size_t)(row0 + wave * 16 + l15) * DIN + quad * 8;
    #pragma unroll 2
    for (int ks = 0; ks < 10; ks++) {
        v8h a = *(const v8h*)(fbase + ks * 32);
        #pragma unroll
        for (int cj = 0; cj < 6; cj++) {
            v8h bf = *(const v8h*)(Wf_o + (size_t)(cj * 10 + ks) * 512 + lane * 8);
            acc[cj] = __builtin_amdgcn_mfma_f32_16x16x32_f16(a, bf, acc[cj], 0, 0, 0);
        }
    }
    #pragma unroll
    for (int cj = 0; cj < 6; cj++) {
        int o = cj * 16 + l15;
        int t = o >> 3, f = o & 7;
        float bb = bzd[o];
        #pragma unroll
        for (int rr = 0; rr < 4; rr++) {
            int row = row0 + wave * 16 + quad * 4 + rr;
            int b = row >> 10, n = row & 1023;
            out[(((size_t)b * TT + t) * NN + n) * FF + f] = acc[cj][rr] + bb;
        }
    }
}

// ---------------- DiffConv operator build ----------------
__global__ void k_deg(const int* __restrict__ ei32, const float* __restrict__ ew,
                      float* __restrict__ degd, float* __restrict__ degs) {
    int e = blockIdx.x * 256 + threadIdx.x;
    float w = ew[e];
    atomicAdd(&degd[ei32[EE + e]], w);
    atomicAdd(&degs[ei32[e]], w);
}
__global__ void k_spadd(const int* __restrict__ ei32, const float* __restrict__ ew,
                        const float* __restrict__ degd, const float* __restrict__ degs,
                        float* __restrict__ temp) {
    int e = blockIdx.x * 256 + threadIdx.x;
    int s = ei32[e], d = ei32[EE + e];
    float w = ew[e];
    float dd = degd[d], ds = degs[s];
    float wfv = dd > 0.f ? w / dd : 0.f;
    float wbv = ds > 0.f ? w / ds : 0.f;
    atomicAdd(&temp[(size_t)d * NN + s], wfv);
    atomicAdd(&temp[(size_t)NN * NN + (size_t)s * NN + d], wbv);
}
__global__ void k_spconv(const float* __restrict__ temp, unsigned short* __restrict__ Mp) {
    size_t i0 = ((size_t)blockIdx.x * 256 + threadIdx.x) * 8;
    size_t dst = (i0 < (size_t)NN * NN) ? i0 : i0 + (size_t)NN * NN;
    unsigned short h8[8];
    #pragma unroll
    for (int j = 0; j < 8; j++) h8[j] = f2h(temp[i0 + j]);
    *(uint4*)(Mp + dst) = *(uint4*)h8;
}

__global__ void k_featd_h(const float* __restrict__ h, unsigned short* __restrict__ featd) {
    size_t idx = (size_t)blockIdx.x * 256 + threadIdx.x;
    size_t row = idx >> 6; int c = (int)(idx & 63);
    featd[row * DIN + c] = f2h(h[idx]);
}

extern "C" void kernel_launch(void* const* d_in, const int* in_sizes, int n_in,
                              void* d_out, int out_size, void* d_ws, size_t ws_size,
                              hipStream_t stream) {
    const float* x      = (const float*)d_in[0];
    const int*   eiraw  = (const int*)  d_in[1];
    const float* ew     = (const float*)d_in[2];
    const float* adj    = (const float*)d_in[3];
    const float* W_enc  = (const float*)d_in[4];
    const float* b_enc  = (const float*)d_in[5];
    const float* emb    = (const float*)d_in[6];
    const float* W_r    = (const float*)d_in[7];
    const float* b_r    = (const float*)d_in[8];
    const float* W_u    = (const float*)d_in[9];
    const float* b_u    = (const float*)d_in[10];
    const float* W_c    = (const float*)d_in[11];
    const float* b_c    = (const float*)d_in[12];
    const float* W_diff = (const float*)d_in[13];
    const float* b_diff = (const float*)d_in[14];
    const float* W_dec  = (const float*)d_in[15];
    const float* b_dec  = (const float*)d_in[16];

    // ---- workspace ~56 MiB ----
    unsigned short* Mf    = (unsigned short*)d_ws;            // 8 MiB
    unsigned short* XhH   = Mf + (size_t)4096 * NN;           // 2 MiB  h fp16 [b][64][n]
    unsigned short* XhR   = XhH + (size_t)BB * 64 * NN;       // 2 MiB  rh fp16
    unsigned short* featd = XhR + (size_t)BB * 64 * NN;       // 10 MiB [16384][320]
    float* h    = (float*)(featd + (size_t)BB * NN * DIN);    // 4 MiB
    float* ubuf = h + (size_t)BB * NN * HH;                   // 4 MiB
    unsigned short* AXall = (unsigned short*)(ubuf + (size_t)BB * NN * HH); // 12 MiB [tb][n][32]
    unsigned short* Mp    = AXall;                            // 8 MiB overlay (prep & readout)
    unsigned short* XallT = AXall + (size_t)192 * NN * 32;    // 3.125 MiB [1600][1024]
    unsigned short* Eg    = XallT + (size_t)1600 * NN;        // 0.5 MiB [4][1024][64]
    float* sptmp  = (float*)(Eg + (size_t)4 * NN * 64);       // 8 MiB
    float* constE = sptmp + (size_t)2 * NN * NN;              // 768 KiB [3][1024][64]
    float* Veg    = constE + (size_t)3 * NN * 64;             // 24 KiB [3][32][64]
    unsigned short* WfH  = (unsigned short*)(Veg + 3 * 32 * 64); // 3*16384 shorts
    unsigned short* WfrH = WfH;
    unsigned short* WfuH = WfH + 16384;
    unsigned short* WfcH = WfH + 32768;
    unsigned short* Wx   = WfH + 49152;                       // 3*2048 shorts
    unsigned short* Wf_o = Wx + 6144;                         // 30720 shorts
    float* bzd  = (float*)(Wf_o + 30720);
    float* rinv = bzd + ODIM;
    float* cinv = rinv + NN;
    int*   eifl = (int*)(cinv + NN);
    int*   ei32 = eifl + 4;
    float* degd = (float*)(ei32 + 2 * EE);
    float* degs = degd + NN;
    float* csum = degs + NN;

    hipMemsetAsync(h, 0, (size_t)BB * NN * HH * 4, stream);
    hipMemsetAsync(XhH, 0, (size_t)BB * 64 * NN * 2, stream);   // h = 0 at t=0
    hipMemsetAsync(csum, 0, NN * 4, stream);

    // ---- build plain M = [Af; Af^2; Ab; Ab^2] (fp16), convert to fragment-major ----
    k_rowsum<<<NN, 256, 0, stream>>>(adj, rinv);
    k_colsumP<<<64, 256, 0, stream>>>(adj, csum);
    k_cinv<<<NN / 256, 256, 0, stream>>>(csum, cinv);
    k_prepA<<<dim3(16, 16), 256, 0, stream>>>(adj, rinv, cinv, Mp);
    k_msq<<<dim3(16, 16, 2), 256, 0, stream>>>(Mp);
    k_m2frag<<<2048, 256, 0, stream>>>(Mp, Mf);

    // ---- x/emb transposes, batched x-hop (overwrites Mp region), const folds ----
    k_xT<<<TT * BB, 256, 0, stream>>>(x, XallT);
    k_embT<<<64, 256, 0, stream>>>(emb, XallT);
    k_hopX<<<13 * 32, 512, 0, stream>>>(Mf, XallT, AXall, Eg);
    k_veg<<<24, 256, 0, stream>>>(W_enc, W_r, W_u, W_c, Veg);
    k_constE<<<dim3(256, 3), 256, 0, stream>>>(Eg, b_enc, W_r, W_u, W_c, constE);
    k_wfragH<<<192, 256, 0, stream>>>(W_r, W_u, W_c, WfrH, WfuH, WfcH);
    k_wfragX<<<24, 256, 0, stream>>>(Veg, Wx);
    k_wfragO<<<120, 256, 0, stream>>>(W_diff, W_dec, Wf_o);
    k_bzd<<<1, ODIM, 0, stream>>>(b_diff, W_dec, b_dec, bzd);

    for (int t = 0; t < TT; t++) {
        const unsigned short* AXt = AXall + (size_t)t * BB * NN * 32;
        // fused: 4 ops @ h + fold -> r,u; rh -> XhR, u -> ubuf
        k_hopRU<<<512, 512, 0, stream>>>(Mf, XhH, AXt, WfrH, WfuH, Wx, Wx + 2048,
                                         b_r, b_u, constE, h, XhR, ubuf);
        // fused: 4 ops @ rh + fold -> c; h update -> h, XhH
        k_hopC<<<512, 512, 0, stream>>>(Mf, XhR, AXt, WfcH, Wx + 4096,
                                        b_c, constE, ubuf, h, XhH);
    }

    // ---- DiffConv readout ----
    k_ei_detect<<<1, 256, 0, stream>>>(eiraw, eifl);
    k_ei_norm<<<2 * EE / 256, 256, 0, stream>>>(eiraw, eifl, ei32);
    hipMemsetAsync(degd, 0, (size_t)2 * NN * 4, stream);
    hipMemsetAsync(sptmp, 0, (size_t)2 * NN * NN * 4, stream);
    k_deg<<<EE / 256, 256, 0, stream>>>(ei32, ew, degd, degs);
    k_spadd<<<EE / 256, 256, 0, stream>>>(ei32, ew, degd, degs, sptmp);
    k_spconv<<<2 * NN * NN / (256 * 8), 256, 0, stream>>>(sptmp, Mp);
    k_msq<<<dim3(16, 16, 2), 256, 0, stream>>>(Mp);
    k_m2frag<<<2048, 256, 0, stream>>>(Mp, Mf);
    k_featd_h<<<BB * NN * HH / 256, 256, 0, stream>>>(h, featd);
    // [Sf;Sf2;Sb;Sb2] @ h (fp16 in XhH) -> featd cols 64 + g*64
    k_hopA<<<8 * 32, 512, 0, stream>>>(Mf, XhH, featd, DIN, 64, 64);
    k_out<<<BB * NN / 64, 256, 0, stream>>>(featd, Wf_o, bzd, (float*)d_out);
}